// Round 18
// baseline (3887.023 us; speedup 1.0000x reference)
//
#include <hip/hip_runtime.h>

#define LRELU(v) ((v) >= 0.f ? (v) : 0.2f * (v))

// ======== implicit-GEMM 3x3 conv, C=64 -> O=64, stride1 pad1, 16x8 tile (4px x 8och) ========
__global__ void conv64_gemm16x8(const float* __restrict__ in, const float* __restrict__ Wt,
                                const float* __restrict__ bias, float* __restrict__ out,
                                int H, int W, int act, int tilesX,
                                long long inStr, long long wStr, long long bStr, long long outStr)
{
    constexpr int CC = 8, TIN = 18, RS = 20;   // 10 rows x 18 cols window
    __shared__ float it[CC * 10 * RS];
    __shared__ float wl[CC * 9 * 64];
    int s = blockIdx.y;
    in   += (size_t)s * inStr;
    Wt   += (size_t)s * wStr;
    bias += (size_t)s * bStr;
    out  += (size_t)s * outStr;

    int b  = blockIdx.x;
    int tx = b % tilesX, ty = b / tilesX;
    int t  = threadIdx.x;
    int og = t >> 5, pg = t & 31;
    int r  = pg >> 2, ch = pg & 3;

    float acc[8][4];
    #pragma unroll
    for (int i = 0; i < 8; ++i)
        #pragma unroll
        for (int j = 0; j < 4; ++j) acc[i][j] = 0.f;

    const int y0 = ty * 8 - 1, x0 = tx * 16 - 1;
    const size_t plane = (size_t)H * W;

    for (int c0 = 0; c0 < 64; c0 += CC) {
        __syncthreads();
        {
            const float4* src = (const float4*)(Wt + c0 * 9 * 64);
            float4* dst = (float4*)wl;
            for (int i = t; i < CC * 9 * 16; i += 256) dst[i] = src[i];
        }
        for (int rowi = t; rowi < CC * 10; rowi += 256) {
            int cc = rowi / 10, rr = rowi - cc * 10;
            int iy = y0 + rr;
            float* dst = it + rowi * RS;
            const float* srow = in + (size_t)(c0 + cc) * plane + (size_t)iy * W + x0;
            if ((unsigned)iy < (unsigned)H && x0 >= 0 && x0 + RS <= W) {
                #pragma unroll
                for (int q = 0; q < 5; ++q)
                    ((float4*)dst)[q] = ((const float4*)srow)[q];
            } else {
                for (int cl = 0; cl < RS; ++cl) {
                    int ix = x0 + cl;
                    float v = 0.f;
                    if (cl < TIN && (unsigned)iy < (unsigned)H && (unsigned)ix < (unsigned)W)
                        v = in[(size_t)(c0 + cc) * plane + (size_t)iy * W + ix];
                    dst[cl] = v;
                }
            }
        }
        __syncthreads();
        for (int cc = 0; cc < CC; ++cc) {
            const float* base = it + cc * 10 * RS;
            #pragma unroll
            for (int ky = 0; ky < 3; ++ky) {
                const float* rowp = base + (r + ky) * RS + ch * 4;
                float4 f0 = *(const float4*)rowp;
                float4 f1 = *(const float4*)(rowp + 4);
                float p[8] = {f0.x, f0.y, f0.z, f0.w, f1.x, f1.y, f1.z, f1.w};
                #pragma unroll
                for (int kx = 0; kx < 3; ++kx) {
                    const float* wp = wl + ((cc * 9) + ky * 3 + kx) * 64 + og * 8;
                    float4 wa = *(const float4*)wp;
                    float4 wb = *(const float4*)(wp + 4);
                    float w8[8] = {wa.x, wa.y, wa.z, wa.w, wb.x, wb.y, wb.z, wb.w};
                    #pragma unroll
                    for (int oi = 0; oi < 8; ++oi)
                        #pragma unroll
                        for (int j = 0; j < 4; ++j)
                            acc[oi][j] += w8[oi] * p[j + kx];
                }
            }
        }
    }

    int y = ty * 8 + r, xb = tx * 16 + ch * 4;
    #pragma unroll
    for (int oi = 0; oi < 8; ++oi) {
        int o = og * 8 + oi;
        float bo = bias[o];
        float v0 = acc[oi][0] + bo, v1 = acc[oi][1] + bo;
        float v2 = acc[oi][2] + bo, v3 = acc[oi][3] + bo;
        if (act) { v0 = LRELU(v0); v1 = LRELU(v1); v2 = LRELU(v2); v3 = LRELU(v3); }
        *(float4*)(out + ((size_t)o * H + y) * W + xb) = make_float4(v0, v1, v2, v3);
    }
}

// ======== implicit-GEMM 3x3 conv, C=64 -> O=64, stride2, 16x8 out tile (4px x 8och) ========
__global__ void conv64s2_gemm16x8(const float* __restrict__ in, const float* __restrict__ Wt,
                                  const float* __restrict__ bias, float* __restrict__ out,
                                  int Hin, int Win, int Hout, int Wout, int pad, int act, int tilesX,
                                  long long inStr, long long wStr, long long bStr, long long outStr)
{
    constexpr int CC = 8, TIN = 35, RS = 36;   // 18 rows x 35 cols window
    __shared__ float it[CC * 18 * RS];
    __shared__ float wl[CC * 9 * 64];
    int s = blockIdx.y;
    in   += (size_t)s * inStr;
    Wt   += (size_t)s * wStr;
    bias += (size_t)s * bStr;
    out  += (size_t)s * outStr;

    int b  = blockIdx.x;
    int tx = b % tilesX, ty = b / tilesX;
    int t  = threadIdx.x;
    int og = t >> 5, pg = t & 31;
    int r  = pg >> 2, ch = pg & 3;

    float acc[8][4];
    #pragma unroll
    for (int i = 0; i < 8; ++i)
        #pragma unroll
        for (int j = 0; j < 4; ++j) acc[i][j] = 0.f;

    const int y0 = 2 * (ty * 8) - pad, x0 = 2 * (tx * 16) - pad;
    const size_t plane = (size_t)Hin * Win;

    for (int c0 = 0; c0 < 64; c0 += CC) {
        __syncthreads();
        {
            const float4* src = (const float4*)(Wt + c0 * 9 * 64);
            float4* dst = (float4*)wl;
            for (int i = t; i < CC * 9 * 16; i += 256) dst[i] = src[i];
        }
        for (int rowi = t; rowi < CC * 18; rowi += 256) {
            int cc = rowi / 18, rr = rowi - cc * 18;
            int iy = y0 + rr;
            float* dst = it + rowi * RS;
            const float* srow = in + (size_t)(c0 + cc) * plane + (size_t)iy * Win + x0;
            if ((unsigned)iy < (unsigned)Hin && x0 >= 0 && x0 + RS <= Win) {
                #pragma unroll
                for (int q = 0; q < 9; ++q)
                    ((float4*)dst)[q] = ((const float4*)srow)[q];
            } else {
                for (int cl = 0; cl < RS; ++cl) {
                    int ix = x0 + cl;
                    float v = 0.f;
                    if (cl < TIN && (unsigned)iy < (unsigned)Hin && (unsigned)ix < (unsigned)Win)
                        v = in[(size_t)(c0 + cc) * plane + (size_t)iy * Win + ix];
                    dst[cl] = v;
                }
            }
        }
        __syncthreads();
        for (int cc = 0; cc < CC; ++cc) {
            const float* base = it + cc * 18 * RS;
            #pragma unroll
            for (int ky = 0; ky < 3; ++ky) {
                const float* rowp = base + (2 * r + ky) * RS + ch * 8;
                float4 f0 = *(const float4*)rowp;
                float4 f1 = *(const float4*)(rowp + 4);
                float4 f2 = *(const float4*)(rowp + 8);
                float p[12] = {f0.x, f0.y, f0.z, f0.w, f1.x, f1.y, f1.z, f1.w,
                               f2.x, f2.y, f2.z, f2.w};
                #pragma unroll
                for (int kx = 0; kx < 3; ++kx) {
                    const float* wp = wl + ((cc * 9) + ky * 3 + kx) * 64 + og * 8;
                    float4 wa = *(const float4*)wp;
                    float4 wb = *(const float4*)(wp + 4);
                    float w8[8] = {wa.x, wa.y, wa.z, wa.w, wb.x, wb.y, wb.z, wb.w};
                    #pragma unroll
                    for (int oi = 0; oi < 8; ++oi)
                        #pragma unroll
                        for (int j = 0; j < 4; ++j)
                            acc[oi][j] += w8[oi] * p[2 * j + kx];
                }
            }
        }
    }

    int y = ty * 8 + r, xb = tx * 16 + ch * 4;
    #pragma unroll
    for (int oi = 0; oi < 8; ++oi) {
        int o = og * 8 + oi;
        float bo = bias[o];
        float v0 = acc[oi][0] + bo, v1 = acc[oi][1] + bo;
        float v2 = acc[oi][2] + bo, v3 = acc[oi][3] + bo;
        if (act) { v0 = LRELU(v0); v1 = LRELU(v1); v2 = LRELU(v2); v3 = LRELU(v3); }
        *(float4*)(out + ((size_t)o * Hout + y) * Wout + xb) = make_float4(v0, v1, v2, v3);
    }
}

// ======== implicit-GEMM 3x3 conv, C=64 -> O=64, stride1 pad1, 8x8 tile ========
__global__ void conv64_gemm8(const float* __restrict__ in, const float* __restrict__ Wt,
                             const float* __restrict__ bias, float* __restrict__ out,
                             int H, int W, int act, int tilesX,
                             long long inStr, long long wStr, long long bStr, long long outStr)
{
    constexpr int CC = 8, TIN = 10, RS = 12;
    __shared__ float it[CC * TIN * RS];
    __shared__ float wl[CC * 9 * 64];
    int s = blockIdx.y;
    in   += (size_t)s * inStr;
    Wt   += (size_t)s * wStr;
    bias += (size_t)s * bStr;
    out  += (size_t)s * outStr;

    int b  = blockIdx.x;
    int tx = b % tilesX, ty = b / tilesX;
    int t  = threadIdx.x;
    int og = t >> 5, pg = t & 31;
    int r  = pg >> 2, ch = pg & 3;

    float acc[8][2];
    #pragma unroll
    for (int i = 0; i < 8; ++i) { acc[i][0] = 0.f; acc[i][1] = 0.f; }

    const int y0 = ty * 8 - 1, x0 = tx * 8 - 1;
    const size_t plane = (size_t)H * W;

    for (int c0 = 0; c0 < 64; c0 += CC) {
        __syncthreads();
        {
            const float4* src = (const float4*)(Wt + c0 * 9 * 64);
            float4* dst = (float4*)wl;
            for (int i = t; i < CC * 9 * 16; i += 256) dst[i] = src[i];
        }
        for (int rowi = t; rowi < CC * TIN; rowi += 256) {
            int cc = rowi / TIN, rr = rowi - cc * TIN;
            int iy = y0 + rr;
            float* dst = it + rowi * RS;
            const float* srow = in + (size_t)(c0 + cc) * plane + (size_t)iy * W + x0;
            if ((unsigned)iy < (unsigned)H && x0 >= 0 && x0 + RS <= W) {
                #pragma unroll
                for (int q = 0; q < 3; ++q)
                    ((float4*)dst)[q] = ((const float4*)srow)[q];
            } else {
                for (int cl = 0; cl < RS; ++cl) {
                    int ix = x0 + cl;
                    float v = 0.f;
                    if (cl < TIN && (unsigned)iy < (unsigned)H && (unsigned)ix < (unsigned)W)
                        v = in[(size_t)(c0 + cc) * plane + (size_t)iy * W + ix];
                    dst[cl] = v;
                }
            }
        }
        __syncthreads();
        for (int cc = 0; cc < CC; ++cc) {
            const float* base = it + cc * TIN * RS;
            #pragma unroll
            for (int ky = 0; ky < 3; ++ky) {
                const float* rowp = base + (r + ky) * RS + ch * 2;
                float p[4] = {rowp[0], rowp[1], rowp[2], rowp[3]};
                #pragma unroll
                for (int kx = 0; kx < 3; ++kx) {
                    const float* wp = wl + ((cc * 9) + ky * 3 + kx) * 64 + og * 8;
                    float4 wa = *(const float4*)wp;
                    float4 wb = *(const float4*)(wp + 4);
                    float w8[8] = {wa.x, wa.y, wa.z, wa.w, wb.x, wb.y, wb.z, wb.w};
                    #pragma unroll
                    for (int oi = 0; oi < 8; ++oi) {
                        acc[oi][0] += w8[oi] * p[kx];
                        acc[oi][1] += w8[oi] * p[kx + 1];
                    }
                }
            }
        }
    }

    int y = ty * 8 + r, xb = tx * 8 + ch * 2;
    #pragma unroll
    for (int oi = 0; oi < 8; ++oi) {
        int o = og * 8 + oi;
        float bo = bias[o];
        float a0 = acc[oi][0] + bo, a1 = acc[oi][1] + bo;
        if (act) { a0 = LRELU(a0); a1 = LRELU(a1); }
        *(float2*)(out + ((size_t)o * H + y) * W + xb) = make_float2(a0, a1);
    }
}

// ======== implicit-GEMM 3x3 conv, C=64 -> O=64, stride2, 8x8 out tile ========
__global__ void conv64s2_gemm8(const float* __restrict__ in, const float* __restrict__ Wt,
                               const float* __restrict__ bias, float* __restrict__ out,
                               int Hin, int Win, int Hout, int Wout, int pad, int act, int tilesX,
                               long long inStr, long long wStr, long long bStr, long long outStr)
{
    constexpr int CC = 8, TIN = 18, RS = 20;
    __shared__ float it[CC * TIN * RS];
    __shared__ float wl[CC * 9 * 64];
    int s = blockIdx.y;
    in   += (size_t)s * inStr;
    Wt   += (size_t)s * wStr;
    bias += (size_t)s * bStr;
    out  += (size_t)s * outStr;

    int b  = blockIdx.x;
    int tx = b % tilesX, ty = b / tilesX;
    int t  = threadIdx.x;
    int og = t >> 5, pg = t & 31;
    int r  = pg >> 2, ch = pg & 3;

    float acc[8][2];
    #pragma unroll
    for (int i = 0; i < 8; ++i) { acc[i][0] = 0.f; acc[i][1] = 0.f; }

    const int y0 = ty * 16 - pad, x0 = tx * 16 - pad;
    const size_t plane = (size_t)Hin * Win;

    for (int c0 = 0; c0 < 64; c0 += CC) {
        __syncthreads();
        {
            const float4* src = (const float4*)(Wt + c0 * 9 * 64);
            float4* dst = (float4*)wl;
            for (int i = t; i < CC * 9 * 16; i += 256) dst[i] = src[i];
        }
        for (int rowi = t; rowi < CC * TIN; rowi += 256) {
            int cc = rowi / TIN, rr = rowi - cc * TIN;
            int iy = y0 + rr;
            float* dst = it + rowi * RS;
            const float* srow = in + (size_t)(c0 + cc) * plane + (size_t)iy * Win + x0;
            if ((unsigned)iy < (unsigned)Hin && x0 >= 0 && x0 + RS <= Win) {
                #pragma unroll
                for (int q = 0; q < RS / 4; ++q)
                    ((float4*)dst)[q] = ((const float4*)srow)[q];
            } else {
                for (int cl = 0; cl < RS; ++cl) {
                    int ix = x0 + cl;
                    float v = 0.f;
                    if (cl < TIN && (unsigned)iy < (unsigned)Hin && (unsigned)ix < (unsigned)Win)
                        v = in[(size_t)(c0 + cc) * plane + (size_t)iy * Win + ix];
                    dst[cl] = v;
                }
            }
        }
        __syncthreads();
        for (int cc = 0; cc < CC; ++cc) {
            const float* base = it + cc * TIN * RS;
            #pragma unroll
            for (int ky = 0; ky < 3; ++ky) {
                const float* rowp = base + (2 * r + ky) * RS + ch * 4;
                float4 f0 = *(const float4*)rowp;
                float4 f1 = *(const float4*)(rowp + 4);
                float p[8] = {f0.x, f0.y, f0.z, f0.w, f1.x, f1.y, f1.z, f1.w};
                #pragma unroll
                for (int kx = 0; kx < 3; ++kx) {
                    const float* wp = wl + ((cc * 9) + ky * 3 + kx) * 64 + og * 8;
                    float4 wa = *(const float4*)wp;
                    float4 wb = *(const float4*)(wp + 4);
                    float w8[8] = {wa.x, wa.y, wa.z, wa.w, wb.x, wb.y, wb.z, wb.w};
                    #pragma unroll
                    for (int oi = 0; oi < 8; ++oi) {
                        acc[oi][0] += w8[oi] * p[kx];
                        acc[oi][1] += w8[oi] * p[kx + 2];
                    }
                }
            }
        }
    }

    int y = ty * 8 + r, xb = tx * 8 + ch * 2;
    #pragma unroll
    for (int oi = 0; oi < 8; ++oi) {
        int o = og * 8 + oi;
        float bo = bias[o];
        float a0 = acc[oi][0] + bo, a1 = acc[oi][1] + bo;
        if (act) { a0 = LRELU(a0); a1 = LRELU(a1); }
        *(float2*)(out + ((size_t)o * Hout + y) * Wout + xb) = make_float2(a0, a1);
    }
}

// ========== implicit-GEMM 3x3 conv, C=3 -> O=64, stride1 pad1 (g0 guide, f0) ==========
__global__ void conv3_gemm(const float* __restrict__ in, const float* __restrict__ Wt,
                           const float* __restrict__ bias, float* __restrict__ out,
                           int H, int W, int tilesX,
                           long long inStr, long long wStr, long long bStr, long long outStr)
{
    constexpr int TIN = 18, RS = 20;
    __shared__ float it[3 * TIN * RS];
    __shared__ float wl[27 * 64];
    int s = blockIdx.y;
    in   += (size_t)s * inStr;
    Wt   += (size_t)s * wStr;
    bias += (size_t)s * bStr;
    out  += (size_t)s * outStr;

    int b  = blockIdx.x;
    int tx = b % tilesX, ty = b / tilesX;
    int t  = threadIdx.x;
    {
        const float4* src = (const float4*)Wt;
        float4* dst = (float4*)wl;
        for (int i = t; i < 27 * 16; i += 256) dst[i] = src[i];
    }
    const int y0 = ty * 16 - 1, x0 = tx * 16 - 1;
    const size_t plane = (size_t)H * W;
    for (int rowi = t; rowi < 3 * TIN; rowi += 256) {
        int cc = rowi / TIN, rr = rowi - cc * TIN;
        int iy = y0 + rr;
        float* dst = it + (size_t)rowi * RS;
        const float* srow = in + (size_t)cc * plane + (size_t)iy * W + x0;
        if ((unsigned)iy < (unsigned)H && x0 >= 0 && x0 + RS <= W) {
            #pragma unroll
            for (int q = 0; q < RS / 4; ++q)
                ((float4*)dst)[q] = ((const float4*)srow)[q];
        } else {
            for (int cl = 0; cl < TIN; ++cl) {
                int ix = x0 + cl;
                float v = 0.f;
                if ((unsigned)iy < (unsigned)H && (unsigned)ix < (unsigned)W)
                    v = in[(size_t)cc * plane + (size_t)iy * W + ix];
                dst[cl] = v;
            }
        }
    }
    __syncthreads();

    int og = t >> 5, pg = t & 31;
    int r  = pg >> 1, ch = pg & 1;
    float acc[8][8];
    #pragma unroll
    for (int i = 0; i < 8; ++i)
        #pragma unroll
        for (int j = 0; j < 8; ++j) acc[i][j] = 0.f;

    for (int c = 0; c < 3; ++c) {
        const float* base = it + c * TIN * RS;
        #pragma unroll
        for (int ky = 0; ky < 3; ++ky) {
            float p[12];
            const float* rowp = base + (r + ky) * RS + ch * 8;
            #pragma unroll
            for (int q = 0; q < 3; ++q) {
                float4 f = *(const float4*)(rowp + q * 4);
                p[q*4+0] = f.x; p[q*4+1] = f.y; p[q*4+2] = f.z; p[q*4+3] = f.w;
            }
            #pragma unroll
            for (int kx = 0; kx < 3; ++kx) {
                const float* wp = wl + ((c * 9) + ky * 3 + kx) * 64 + og * 8;
                float4 wa = *(const float4*)wp;
                float4 wb = *(const float4*)(wp + 4);
                float w8[8] = {wa.x, wa.y, wa.z, wa.w, wb.x, wb.y, wb.z, wb.w};
                #pragma unroll
                for (int oi = 0; oi < 8; ++oi)
                    #pragma unroll
                    for (int j = 0; j < 8; ++j)
                        acc[oi][j] += w8[oi] * p[j + kx];
            }
        }
    }

    int y  = ty * 16 + r;
    int xb = tx * 16 + ch * 8;
    #pragma unroll
    for (int oi = 0; oi < 8; ++oi) {
        int o = og * 8 + oi;
        float bo = bias[o];
        float v[8];
        #pragma unroll
        for (int j = 0; j < 8; ++j) {
            float a = acc[oi][j] + bo;
            v[j] = LRELU(a);
        }
        float* op = out + ((size_t)o * H + y) * W + xb;
        *(float4*)op       = make_float4(v[0], v[1], v[2], v[3]);
        *(float4*)(op + 4) = make_float4(v[4], v[5], v[6], v[7]);
    }
}

// ========== implicit-GEMM 3x3 conv, C=64 -> O=3, (in1+in2), no act (c6) ==========
__global__ void conv64to3_gemm(const float* __restrict__ in, const float* __restrict__ in2,
                               const float* __restrict__ Wt, const float* __restrict__ sb,
                               float* __restrict__ out, int H, int W, int tilesX,
                               long long inStr, long long wStr, long long sbStr, long long outStr)
{
    constexpr int CC = 8, TIN = 18, RS = 20;
    __shared__ float it[CC * TIN * RS];
    __shared__ float wl[CC * 9 * 3];
    int s = blockIdx.y;
    in  += (size_t)s * inStr;
    in2 += (size_t)s * inStr;
    Wt  += (size_t)s * wStr;
    sb  += (size_t)s * sbStr;
    out += (size_t)s * outStr;

    int b  = blockIdx.x;
    int tx = b % tilesX, ty = b / tilesX;
    int t  = threadIdx.x;
    int r  = t >> 4, cl = t & 15;
    const int y0 = ty * 16 - 1, x0 = tx * 16 - 1;
    const size_t plane = (size_t)H * W;

    float acc[3] = {0.f, 0.f, 0.f};

    for (int c0 = 0; c0 < 64; c0 += CC) {
        __syncthreads();
        for (int i = t; i < CC * 9 * 3; i += 256) wl[i] = Wt[c0 * 27 + i];
        for (int rowi = t; rowi < CC * TIN; rowi += 256) {
            int cc = rowi / TIN, rr = rowi - cc * TIN;
            int iy = y0 + rr;
            float* dst = it + (size_t)rowi * RS;
            size_t roff = (size_t)(c0 + cc) * plane + (size_t)iy * W + x0;
            if ((unsigned)iy < (unsigned)H && x0 >= 0 && x0 + RS <= W) {
                #pragma unroll
                for (int q = 0; q < RS / 4; ++q) {
                    float4 a = ((const float4*)(in  + roff))[q];
                    float4 bb = ((const float4*)(in2 + roff))[q];
                    ((float4*)dst)[q] = make_float4(a.x + bb.x, a.y + bb.y, a.z + bb.z, a.w + bb.w);
                }
            } else {
                for (int c2 = 0; c2 < TIN; ++c2) {
                    int ix = x0 + c2;
                    float v = 0.f;
                    if ((unsigned)iy < (unsigned)H && (unsigned)ix < (unsigned)W) {
                        size_t off = (size_t)(c0 + cc) * plane + (size_t)iy * W + ix;
                        v = in[off] + in2[off];
                    }
                    dst[c2] = v;
                }
            }
        }
        __syncthreads();
        for (int cc = 0; cc < CC; ++cc) {
            const float* base = it + cc * TIN * RS;
            #pragma unroll
            for (int ky = 0; ky < 3; ++ky) {
                const float* rowp = base + (r + ky) * RS + cl;
                float p0 = rowp[0], p1 = rowp[1], p2 = rowp[2];
                const float* wr = wl + (cc * 9 + ky * 3) * 3;
                #pragma unroll
                for (int o = 0; o < 3; ++o)
                    acc[o] += wr[o] * p0 + wr[3 + o] * p1 + wr[6 + o] * p2;
            }
        }
    }

    int y = ty * 16 + r, x = tx * 16 + cl;
    #pragma unroll
    for (int o = 0; o < 3; ++o)
        out[((size_t)o * H + y) * W + x] = acc[o] + sb[o];
}

// ===== fused up-conv: tconv(s2,3x3)+blur(4x4,x4/64)+bias+lrelu, 32x8 tile, LDS-staged stores =====
// Round-14 proven config: lane map t = og[0:2]|pxb[3]|xh[4]|r[5:7], PSTR=68, separate ost.
__global__ void upconv64_gemm(const float* __restrict__ in, const float* __restrict__ in2,
                              const float* __restrict__ G2, const float* __restrict__ sb,
                              float* __restrict__ out, int Hin, int Win, int tilesX,
                              long long bufStr, long long sbStr, long long outStr)
{
    constexpr int CC = 4;
    constexpr int RS = 20;                    // 18-col window, padded
    constexpr int PSTR = 68;                  // padded parity stride (floats)
    extern __shared__ float lds[];
    float* it  = lds;                         // [CC][6][RS] = 480
    float* wl  = lds + CC * 6 * RS;           // [CC][9][4][PSTR] = CC*2448
    float* ost = wl + CC * 2448;              // [64][33] = 2112

    int s = blockIdx.y;
    in  += (size_t)s * bufStr;
    in2 += (size_t)s * bufStr;
    G2  += (size_t)s * bufStr;
    sb  += (size_t)s * sbStr;
    out += (size_t)s * outStr;

    int b  = blockIdx.x;
    int tx = b % tilesX, ty = b / tilesX;
    int t  = threadIdx.x;
    int og  = t & 7;
    int pxb = (t >> 3) & 1;
    int xh  = (t >> 4) & 1;
    int r   = t >> 5;                         // out row 0..7
    int rhalf = r >> 1, rpar = r & 1;
    const int Y0 = ty * 8, X0 = tx * 32;
    const int gy0 = Y0 / 2 - 1;
    const int gx0 = X0 / 2 - 1;
    const size_t plane = (size_t)Hin * Win;

    float acc[8][8];
    #pragma unroll
    for (int i = 0; i < 8; ++i)
        #pragma unroll
        for (int j = 0; j < 8; ++j) acc[i][j] = 0.f;

    for (int c0 = 0; c0 < 64; c0 += CC) {
        __syncthreads();
        {
            const float4* src = (const float4*)(G2 + (size_t)c0 * 2304);
            for (int i = t; i < CC * 36 * 16; i += 256) {
                int row = i >> 4, q = i & 15;
                ((float4*)(wl + row * PSTR))[q] = src[i];
            }
        }
        for (int rowi = t; rowi < CC * 6; rowi += 256) {
            int cc = rowi / 6, rr = rowi - cc * 6;
            int gi = gy0 + rr;
            float* dst = it + (size_t)rowi * RS;
            size_t roff = (size_t)(c0 + cc) * plane + (size_t)gi * Win + gx0;
            if ((unsigned)gi < (unsigned)Hin && gx0 >= 0 && gx0 + RS <= Win) {
                #pragma unroll
                for (int qq = 0; qq < 5; ++qq) {
                    float4 a = ((const float4*)(in  + roff))[qq];
                    float4 bb = ((const float4*)(in2 + roff))[qq];
                    ((float4*)dst)[qq] = make_float4(a.x + bb.x, a.y + bb.y, a.z + bb.z, a.w + bb.w);
                }
            } else {
                for (int cl = 0; cl < RS; ++cl) {
                    int gj = gx0 + cl;
                    float v = 0.f;
                    if (cl < 18 && (unsigned)gi < (unsigned)Hin && (unsigned)gj < (unsigned)Win) {
                        size_t off = (size_t)(c0 + cc) * plane + (size_t)gi * Win + gj;
                        v = in[off] + in2[off];
                    }
                    dst[cl] = v;
                }
            }
        }
        __syncthreads();
        for (int cc = 0; cc < CC; ++cc) {
            const float* ib = it + cc * 6 * RS;
            const float* wcb = wl + cc * (36 * PSTR) + (rpar * 2 + pxb) * PSTR;
            #pragma unroll
            for (int ty2 = 0; ty2 < 3; ++ty2) {
                float p[12];
                const float* rowp = ib + (rhalf + ty2) * RS + xh * 8;
                #pragma unroll
                for (int qq = 0; qq < 3; ++qq) {
                    float4 f = *(const float4*)(rowp + qq * 4);
                    p[qq*4+0] = f.x; p[qq*4+1] = f.y; p[qq*4+2] = f.z; p[qq*4+3] = f.w;
                }
                #pragma unroll
                for (int tx2 = 0; tx2 < 3; ++tx2) {
                    const float* wp = wcb + (ty2 * 3 + tx2) * (4 * PSTR) + og * 8;
                    float4 wa = *(const float4*)wp;
                    float4 wv = *(const float4*)(wp + 4);
                    float w8[8] = {wa.x, wa.y, wa.z, wa.w, wv.x, wv.y, wv.z, wv.w};
                    #pragma unroll
                    for (int oi = 0; oi < 8; ++oi)
                        #pragma unroll
                        for (int k = 0; k < 8; ++k)
                            acc[oi][k] += w8[oi] * p[k + tx2];
                }
            }
        }
    }

    const int Hout = 2 * Hin, Wout = 2 * Win;
    const int obase = (r * 8 + og) * 33 + xh * 16 + pxb;
    #pragma unroll
    for (int oi = 0; oi < 8; ++oi) {
        int o = og * 8 + oi;
        float bo = sb[o];
        __syncthreads();
        #pragma unroll
        for (int k = 0; k < 8; ++k) {
            float a = acc[oi][k] + bo;
            ost[obase + 2 * k] = LRELU(a);
        }
        __syncthreads();
        #pragma unroll
        for (int p2 = 0; p2 < 2; ++p2) {
            int j4 = p2 * 256 + t;
            int ogr = j4 >> 6;
            int rr  = (j4 >> 3) & 7;
            int x4  = j4 & 7;
            const float* sp = ost + (rr * 8 + ogr) * 33 + x4 * 4;
            float4 f = make_float4(sp[0], sp[1], sp[2], sp[3]);
            int oo = ogr * 8 + oi;
            *(float4*)(out + ((size_t)oo * Hout + Y0 + rr) * Wout + X0 + x4 * 4) = f;
        }
    }
}

// ------- build combined up-weights, layout [c][tap][parity][o] -------
__global__ void combine_up_w(const float* __restrict__ W, float* __restrict__ G2,
                             long long wStr, long long g2Str)
{
    int s = blockIdx.y;
    W  += (size_t)s * wStr;
    G2 += (size_t)s * g2Str;
    int i = blockIdx.x * 256 + threadIdx.x;
    if (i >= 147456) return;
    int o = i & 63;
    int rest = i >> 6;
    int p4 = rest & 3;
    int k9 = (rest >> 2) % 9;
    int c  = (rest >> 2) / 9;
    int py = p4 >> 1, px = p4 & 1;
    int tyk = k9 / 3, txk = k9 % 3;
    int dy = 2 * tyk - 1 - py, dx = 2 * txk - 1 - px;
    const float K[4] = {1.f, 3.f, 3.f, 1.f};
    const float* wp = W + ((size_t)o * 64 + c) * 9;
    float sacc = 0.f;
    #pragma unroll
    for (int a = 0; a < 3; ++a) {
        int ky = a + dy;
        if ((unsigned)ky >= 4u) continue;
        #pragma unroll
        for (int b2 = 0; b2 < 3; ++b2) {
            int kx = b2 + dx;
            if ((unsigned)kx >= 4u) continue;
            sacc += K[ky] * K[kx] * wp[a * 3 + b2];
        }
    }
    G2[i] = sacc * (1.f / 16.f);
}

// ---------------- 4x4 blur pad=2 (pre-down), batched ----------------
__global__ void blur_down(const float* __restrict__ in, float* __restrict__ out,
                          int H, int W, int tilesX, int tilesY,
                          long long inStr, long long outStr)
{
    int s = blockIdx.y;
    in  += (size_t)s * inStr;
    out += (size_t)s * outStr;
    int Ho = H + 1, Wo = W + 1;
    int bid = blockIdx.x;
    int tx = bid % tilesX; bid /= tilesX;
    int ty = bid % tilesY; bid /= tilesY;
    int p  = bid;
    int x = tx * 16 + (threadIdx.x & 15);
    int y = ty * 16 + (threadIdx.x >> 4);
    if (x >= Wo || y >= Ho) return;
    const float k[4] = {1.f, 3.f, 3.f, 1.f};
    const float* ip = in + (size_t)p * H * W;
    float acc = 0.f;
    #pragma unroll
    for (int ky = 0; ky < 4; ++ky) {
        int iy = y - 2 + ky;
        if ((unsigned)iy >= (unsigned)H) continue;
        float row = 0.f;
        #pragma unroll
        for (int kx = 0; kx < 4; ++kx) {
            int ix = x - 2 + kx;
            if ((unsigned)ix >= (unsigned)W) continue;
            row += ip[(size_t)iy * W + ix] * k[kx];
        }
        acc += row * k[ky];
    }
    out[((size_t)p * Ho + y) * Wo + x] = acc * (1.f / 64.f);
}

// ---------------- avg pool to 1x1 (64 planes), batched ----------------
__global__ void avgpool_hw(const float* __restrict__ in, float* __restrict__ out, int HW,
                           long long inStr, long long outStr)
{
    int s = blockIdx.y;
    in  += (size_t)s * inStr;
    out += (size_t)s * outStr;
    int p = blockIdx.x;
    const float* ip = in + (size_t)p * HW;
    float sum = 0.f;
    for (int i = threadIdx.x; i < HW; i += blockDim.x) sum += ip[i];
    __shared__ float red[256];
    red[threadIdx.x] = sum;
    __syncthreads();
    for (int off = 128; off; off >>= 1) {
        if ((int)threadIdx.x < off) red[threadIdx.x] += red[threadIdx.x + off];
        __syncthreads();
    }
    if (threadIdx.x == 0) out[p] = red[0] / (float)HW;
}

// ---------------- style FC (single layer) ----------------
__global__ void style_fc(const float* __restrict__ s, const float* __restrict__ W,
                         const float* __restrict__ b, float* __restrict__ out, int outdim)
{
    int n = blockIdx.x;
    int i = threadIdx.x;
    if (i >= outdim) return;
    float acc = b[i];
    const float* sn = s + n * 64;
    const float* wi = W + i * 64;
    for (int f = 0; f < 64; ++f) acc += sn[f] * wi[f];
    out[n * 64 + i] = LRELU(acc);
}

// ------- merged style FC for the 10 mid layers: grid (8 samples, 10 layers, 2 sw/sb) -------
__global__ void style_fc_mids(const float* __restrict__ s,
                              const float* __restrict__ midswW, const float* __restrict__ midswb,
                              const float* __restrict__ midsbW, const float* __restrict__ midsbb,
                              float* __restrict__ sty)
{
    int n = blockIdx.x, li = blockIdx.y, z = blockIdx.z;
    const float* W = (z ? midsbW : midswW) + (size_t)li * 4096;
    const float* b = (z ? midsbb : midswb) + (size_t)li * 64;
    float* out = sty + (size_t)(1 + li) * 1024 + z * 512;
    int i = threadIdx.x;
    float acc = b[i];
    const float* sn = s + n * 64;
    const float* wi = W + i * 64;
    for (int f = 0; f < 64; ++f) acc += sn[f] * wi[f];
    out[n * 64 + i] = LRELU(acc);
}

// ------- modulate+demodulate (single layer, all 8 samples); transpose=1 -> [c][k][o] -------
__global__ void modulate(const float* __restrict__ w, const float* __restrict__ sw,
                         float* __restrict__ wout, int O, int C, int transpose)
{
    int no = blockIdx.x;
    int o = no % O, n = no / O;
    int nw = C * 9;
    int t = threadIdx.x;
    float v[9];
    int cnt = 0;
    float ss = 0.f;
    for (int idx = t; idx < nw; idx += 64) {
        int c = idx / 9;
        float val = w[o * nw + idx] * sw[n * 64 + c];
        v[cnt++] = val;
        ss += val * val;
    }
    #pragma unroll
    for (int off = 32; off; off >>= 1) ss += __shfl_xor(ss, off);
    float d = rsqrtf(ss + 1e-8f);
    cnt = 0;
    for (int idx = t; idx < nw; idx += 64) {
        float val = v[cnt++] * d;
        if (transpose)
            wout[(size_t)n * nw * O + (size_t)idx * O + o] = val;
        else
            wout[(size_t)no * nw + idx] = val;
    }
}

// ------- merged modulate for the 10 mid layers: grid (512, 10). trf=0 for li in {6,8} -------
__global__ void modulate_mids(const float* __restrict__ midw, const float* __restrict__ sty,
                              float* __restrict__ wmBase)
{
    int li = blockIdx.y;
    const float* w  = midw + (size_t)li * 36864;
    const float* sw = sty + (size_t)(1 + li) * 1024;
    float* wout = wmBase + (size_t)li * 294912;
    int transpose = !(li == 6 || li == 8);
    int no = blockIdx.x;
    int o = no & 63, n = no >> 6;
    int t = threadIdx.x;
    float v[9];
    int cnt = 0;
    float ss = 0.f;
    for (int idx = t; idx < 576; idx += 64) {
        int c = idx / 9;
        float val = w[o * 576 + idx] * sw[n * 64 + c];
        v[cnt++] = val;
        ss += val * val;
    }
    #pragma unroll
    for (int off = 32; off; off >>= 1) ss += __shfl_xor(ss, off);
    float d = rsqrtf(ss + 1e-8f);
    cnt = 0;
    for (int idx = t; idx < 576; idx += 64) {
        float val = v[cnt++] * d;
        if (transpose)
            wout[(size_t)n * 576 * 64 + (size_t)idx * 64 + o] = val;
        else
            wout[((size_t)n * 64 + o) * 576 + idx] = val;
    }
}

// ------- guide weight transpose -------
__global__ void guide_transpose(const float* __restrict__ grw, float* __restrict__ gt, int total)
{
    int i = blockIdx.x * 256 + threadIdx.x;
    if (i >= total) return;
    int l = i / 36864, rem = i % 36864;
    int idx = rem / 64, o = rem % 64;
    int c = idx / 9, k = idx % 9;
    gt[i] = grw[(((size_t)l * 64 + o) * 64 + c) * 9 + k];
}

// ------- g0 weight transpose -------
__global__ void g0_transpose(const float* __restrict__ g0w, float* __restrict__ gt)
{
    int i = blockIdx.x * 256 + threadIdx.x;
    if (i >= 1728) return;
    int idx = i / 64, o = i % 64;
    int c = idx / 9, k = idx % 9;
    gt[i] = g0w[((size_t)o * 3 + c) * 9 + k];
}

__global__ void fill_sentinel(float* __restrict__ out, int n)
{
    int i = blockIdx.x * 256 + threadIdx.x;
    if (i < n) out[i] = 1.0e9f;
}

extern "C" void kernel_launch(void* const* d_in, const int* in_sizes, int n_in,
                              void* d_out, int out_size, void* d_ws, size_t ws_size,
                              hipStream_t stream)
{
    const float* x     = (const float*)d_in[0];
    const float* ref   = (const float*)d_in[1];
    const float* g0w   = (const float*)d_in[2];
    const float* g0b   = (const float*)d_in[3];
    const float* grw   = (const float*)d_in[4];
    const float* grb   = (const float*)d_in[5];
    const float* c0w   = (const float*)d_in[6];
    const float* c0swW = (const float*)d_in[7];
    const float* c0swb = (const float*)d_in[8];
    const float* c0sbW = (const float*)d_in[9];
    const float* c0sbb = (const float*)d_in[10];
    const float* midw  = (const float*)d_in[11];
    const float* midswW= (const float*)d_in[12];
    const float* midswb= (const float*)d_in[13];
    const float* midsbW= (const float*)d_in[14];
    const float* midsbb= (const float*)d_in[15];
    const float* c6w   = (const float*)d_in[16];
    const float* c6swW = (const float*)d_in[17];
    const float* c6swb = (const float*)d_in[18];
    const float* c6sbW = (const float*)d_in[19];
    const float* c6sbb = (const float*)d_in[20];
    float* out = (float*)d_out;
    float* ws  = (float*)d_ws;

    // -------- shared region (floats) --------
    const size_t SV  = 0;
    const size_t STY = 512;
    const size_t WM  = 12800;
    const size_t GT  = 2989568;
    const size_t G0T = 3137024;
    const size_t BUF = 3138816;

    // -------- main-path per-sample slot offsets --------
    const size_t SA = 0;                  // [64,257,257]-class
    const size_t SB = 4227136;            // [64,256,256]
    const size_t D1 = 8421440;            // [64,128,128]
    const size_t D2 = 9470016;            // [64,128,128]
    const size_t D3 = 10518592;           // [64,129,129]-class
    const size_t E1 = 11583616;           // [64,64,64]
    const size_t E2 = 11845760;
    const size_t E3 = 12107904;
    const size_t G2o = 12107904;          // combined up-weights [147456], ALIASES E3 (dead by f4up)
    const long long PER = 12370048ll;     // ~49.5 MB per sample

    // -------- guide-phase per-sample slot offsets --------
    const size_t gSA = 0;
    const size_t gD1 = 4194304;
    const size_t gD2 = 5242880;
    const size_t gE1 = 6291456;
    const size_t gE2 = 6553600;
    const long long GPER = 6815744ll;

    int G = 0, GG = 0;
    for (int g = 8; g >= 1; --g)
        if ((BUF + (size_t)g * PER) * sizeof(float) <= ws_size) { G = g; break; }
    for (int g = 8; g >= 1; --g)
        if ((BUF + (size_t)g * GPER) * sizeof(float) <= ws_size) { GG = g; break; }
    if (!G || !GG) {
        fill_sentinel<<<dim3((out_size + 255) / 256), dim3(256), 0, stream>>>(out, out_size);
        return;
    }

    dim3 blk(256);
    const int LDSU = (4 * 6 * 20 + 4 * 2448 + 2112) * 4;   // 49536 B (round-14 proven)

    float* B = ws + BUF;

    guide_transpose<<<dim3(147456 / 256), blk, 0, stream>>>(grw, ws + GT, 147456);
    g0_transpose<<<dim3(7), blk, 0, stream>>>(g0w, ws + G0T);

    // ==================== guide net ====================
    for (int n0 = 0; n0 < 8; ) {
        int g = (8 - n0 < GG) ? (8 - n0) : GG;
        const float* refg = ref + (size_t)n0 * 196608;
        conv3_gemm<<<dim3(16 * 16, g), blk, 0, stream>>>(
            refg, ws + G0T, g0b, B + gSA, 256, 256, 16, 196608, 0, 0, GPER);
        conv64s2_gemm16x8<<<dim3(8 * 16, g), blk, 0, stream>>>(
            B + gSA, ws + GT, grb, B + gD1, 256, 256, 128, 128, 1, 1, 8, GPER, 0, 0, GPER);
        conv64_gemm16x8<<<dim3(8 * 16, g), blk, 0, stream>>>(
            B + gD1, ws + GT + 36864, grb + 64, B + gD2, 128, 128, 1, 8, GPER, 0, 0, GPER);
        conv64s2_gemm8<<<dim3(8 * 8, g), blk, 0, stream>>>(
            B + gD2, ws + GT + 73728, grb + 128, B + gE1, 128, 128, 64, 64, 1, 1, 8, GPER, 0, 0, GPER);
        conv64_gemm8<<<dim3(8 * 8, g), blk, 0, stream>>>(
            B + gE1, ws + GT + 110592, grb + 192, B + gE2, 64, 64, 0, 8, GPER, 0, 0, GPER);
        avgpool_hw<<<dim3(64, g), blk, 0, stream>>>(B + gE2, ws + SV + (size_t)n0 * 64, 4096, GPER, 64);
        n0 += g;
    }

    // ==================== styles + modulated weights ====================
    style_fc<<<dim3(8), dim3(64), 0, stream>>>(ws + SV, c0swW, c0swb, ws + STY + 0 * 1024, 3);
    style_fc<<<dim3(8), dim3(64), 0, stream>>>(ws + SV, c0sbW, c0sbb, ws + STY + 0 * 1024 + 512, 64);
    modulate<<<dim3(8 * 64), dim3(64), 0, stream>>>(c0w, ws + STY + 0 * 1024, ws + WM, 64, 3, 1);
    style_fc_mids<<<dim3(8, 10, 2), dim3(64), 0, stream>>>(
        ws + SV, midswW, midswb, midsbW, midsbb, ws + STY);
    modulate_mids<<<dim3(512, 10), dim3(64), 0, stream>>>(midw, ws + STY, ws + WM + 13824);
    style_fc<<<dim3(8), dim3(64), 0, stream>>>(ws + SV, c6swW, c6swb, ws + STY + 11 * 1024, 64);
    style_fc<<<dim3(8), dim3(64), 0, stream>>>(ws + SV, c6sbW, c6sbb, ws + STY + 11 * 1024 + 512, 3);
    modulate<<<dim3(8 * 3), dim3(64), 0, stream>>>(c6w, ws + STY + 11 * 1024, ws + WM + 13824 + 2949120, 3, 64, 1);

    size_t wmo[12];
    int Ci[12], Oi[12];
    wmo[0] = WM; Ci[0] = 3; Oi[0] = 64;
    for (int i = 0; i < 10; ++i) { wmo[1 + i] = WM + 13824ull + (size_t)i * 294912ull; Ci[1 + i] = 64; Oi[1 + i] = 64; }
    wmo[11] = WM + 13824ull + 2949120ull; Ci[11] = 64; Oi[11] = 3;

    // ==================== main path ====================
    for (int n0 = 0; n0 < 8; ) {
        int g = (8 - n0 < G) ? (8 - n0) : G;
        const float* xg = x + (size_t)n0 * 196608;
        float* outg = out + (size_t)n0 * 196608;
        #define WN(i)  (ws + wmo[i] + (size_t)n0 * Oi[i] * Ci[i] * 9)
        #define WSTR(i) ((long long)(Oi[i] * Ci[i] * 9))
        #define SBN(i) (ws + STY + (i) * 1024 + 512 + (size_t)n0 * 64)
        // f0 -> SB
        conv3_gemm<<<dim3(16 * 16, g), blk, 0, stream>>>(
            xg, WN(0), SBN(0), B + SB, 256, 256, 16, 196608, WSTR(0), 64, PER);
        // f1 down: blur(SB) -> SA; conv s2 -> D1; conv -> D2
        blur_down<<<dim3(64 * 17 * 17, g), blk, 0, stream>>>(B + SB, B + SA, 256, 256, 17, 17, PER, PER);
        conv64s2_gemm16x8<<<dim3(8 * 16, g), blk, 0, stream>>>(
            B + SA, WN(1), SBN(1), B + D1, 257, 257, 128, 128, 0, 1, 8, PER, WSTR(1), 64, PER);
        conv64_gemm16x8<<<dim3(8 * 16, g), blk, 0, stream>>>(
            B + D1, WN(2), SBN(2), B + D2, 128, 128, 1, 8, PER, WSTR(2), 64, PER);
        // f2 down
        blur_down<<<dim3(64 * 9 * 9, g), blk, 0, stream>>>(B + D2, B + D3, 128, 128, 9, 9, PER, PER);
        conv64s2_gemm8<<<dim3(8 * 8, g), blk, 0, stream>>>(
            B + D3, WN(3), SBN(3), B + E1, 129, 129, 64, 64, 0, 1, 8, PER, WSTR(3), 64, PER);
        conv64_gemm8<<<dim3(8 * 8, g), blk, 0, stream>>>(
            B + E1, WN(4), SBN(4), B + E2, 64, 64, 1, 8, PER, WSTR(4), 64, PER);
        // f3 x2
        conv64_gemm8<<<dim3(8 * 8, g), blk, 0, stream>>>(
            B + E2, WN(5), SBN(5), B + E3, 64, 64, 1, 8, PER, WSTR(5), 64, PER);
        conv64_gemm8<<<dim3(8 * 8, g), blk, 0, stream>>>(
            B + E3, WN(6), SBN(6), B + E1, 64, 64, 1, 8, PER, WSTR(6), 64, PER);
        // f4 up (fused): combine -> G2o (aliases dead E3); upconv(f3+f2) -> D1; conv -> D3
        combine_up_w<<<dim3(576, g), blk, 0, stream>>>(WN(7), B + G2o, WSTR(7), PER);
        upconv64_gemm<<<dim3(4 * 16, g), blk, LDSU, stream>>>(
            B + E1, B + E2, B + G2o, SBN(7), B + D1, 64, 64, 4, PER, 64, PER);
        conv64_gemm16x8<<<dim3(8 * 16, g), blk, 0, stream>>>(
            B + D1, WN(8), SBN(8), B + D3, 128, 128, 1, 8, PER, WSTR(8), 64, PER);
        // f5 up: combine -> G2o; upconv(f4+f1) -> SA (256^2, tiles 8x32); conv -> SB
        combine_up_w<<<dim3(576, g), blk, 0, stream>>>(WN(9), B + G2o, WSTR(9), PER);
        upconv64_gemm<<<dim3(8 * 32, g), blk, LDSU, stream>>>(
            B + D3, B + D2, B + G2o, SBN(9), B + SA, 128, 128, 8, PER, 64, PER);
        conv64_gemm16x8<<<dim3(16 * 32, g), blk, 0, stream>>>(
            B + SA, WN(10), SBN(10), B + SB, 256, 256, 1, 16, PER, WSTR(10), 64, PER);
        // recompute f0 -> SA
        conv3_gemm<<<dim3(16 * 16, g), blk, 0, stream>>>(
            xg, WN(0), SBN(0), B + SA, 256, 256, 16, 196608, WSTR(0), 64, PER);
        // c6: conv(f5 + f0) -> out
        conv64to3_gemm<<<dim3(16 * 16, g), blk, 0, stream>>>(
            B + SB, B + SA, WN(11), SBN(11), outg, 256, 256, 16, PER, WSTR(11), 64, 196608);
        #undef WN
        #undef WSTR
        #undef SBN
        n0 += g;
    }
}

// Round 19
// 3830.941 us; speedup vs baseline: 1.0146x; 1.0146x over previous
//
#include <hip/hip_runtime.h>

#define LRELU(v) ((v) >= 0.f ? (v) : 0.2f * (v))

// ================= implicit-GEMM 3x3 conv, C=64 -> O=64, 16x16 tile (stride 1) =================
template<int S>
__global__ void conv64_gemm(const float* __restrict__ in, const float* __restrict__ Wt,
                            const float* __restrict__ bias, float* __restrict__ out,
                            int Hin, int Win, int Hout, int Wout, int pad, int act, int tilesX,
                            long long inStr, long long wStr, long long bStr, long long outStr)
{
    constexpr int CC  = (S == 1) ? 8 : 4;
    constexpr int TIN = (S == 1) ? 18 : 33;
    constexpr int RS  = (S == 1) ? 20 : 36;
    constexpr int NF4 = (S == 1) ? 3 : 5;
    constexpr int PW  = NF4 * 4;
    extern __shared__ float lds[];
    float* it = lds;
    float* wl = lds + CC * TIN * RS;

    int s = blockIdx.y;
    in   += (size_t)s * inStr;
    Wt   += (size_t)s * wStr;
    bias += (size_t)s * bStr;
    out  += (size_t)s * outStr;

    int b  = blockIdx.x;
    int tx = b % tilesX, ty = b / tilesX;
    int t  = threadIdx.x;
    int og = t >> 5;
    int pg = t & 31;
    int r  = pg >> 1, ch = pg & 1;

    float acc[8][8];
    #pragma unroll
    for (int i = 0; i < 8; ++i)
        #pragma unroll
        for (int j = 0; j < 8; ++j) acc[i][j] = 0.f;

    const int y0 = ty * 16 * S - pad;
    const int x0 = tx * 16 * S - pad;
    const size_t plane = (size_t)Hin * Win;

    for (int c0 = 0; c0 < 64; c0 += CC) {
        __syncthreads();
        {
            const float4* src = (const float4*)(Wt + c0 * 9 * 64);
            float4* dst = (float4*)wl;
            for (int i = t; i < CC * 9 * 16; i += 256) dst[i] = src[i];
        }
        for (int rowi = t; rowi < CC * TIN; rowi += 256) {
            int cc = rowi / TIN, rr = rowi - cc * TIN;
            int iy = y0 + rr;
            float* dst = it + (size_t)rowi * RS;
            const float* srow = in + (size_t)(c0 + cc) * plane + (size_t)iy * Win + x0;
            if ((unsigned)iy < (unsigned)Hin && x0 >= 0 && x0 + RS <= Win) {
                #pragma unroll
                for (int q = 0; q < RS / 4; ++q)
                    ((float4*)dst)[q] = ((const float4*)srow)[q];
            } else {
                for (int cl = 0; cl < TIN; ++cl) {
                    int ix = x0 + cl;
                    float v = 0.f;
                    if ((unsigned)iy < (unsigned)Hin && (unsigned)ix < (unsigned)Win)
                        v = in[(size_t)(c0 + cc) * plane + (size_t)iy * Win + ix];
                    dst[cl] = v;
                }
            }
        }
        __syncthreads();
        for (int cc = 0; cc < CC; ++cc) {
            const float* base = it + cc * TIN * RS;
            #pragma unroll
            for (int ky = 0; ky < 3; ++ky) {
                float p[PW];
                const float* rowp = base + (r * S + ky) * RS + ch * 8 * S;
                #pragma unroll
                for (int q = 0; q < NF4; ++q) {
                    float4 f = *(const float4*)(rowp + q * 4);
                    p[q*4+0] = f.x; p[q*4+1] = f.y; p[q*4+2] = f.z; p[q*4+3] = f.w;
                }
                #pragma unroll
                for (int kx = 0; kx < 3; ++kx) {
                    const float* wp = wl + ((cc * 9) + ky * 3 + kx) * 64 + og * 8;
                    float4 wa = *(const float4*)wp;
                    float4 wb = *(const float4*)(wp + 4);
                    float w8[8] = {wa.x, wa.y, wa.z, wa.w, wb.x, wb.y, wb.z, wb.w};
                    #pragma unroll
                    for (int oi = 0; oi < 8; ++oi)
                        #pragma unroll
                        for (int j = 0; j < 8; ++j)
                            acc[oi][j] += w8[oi] * p[j * S + kx];
                }
            }
        }
    }

    int y  = ty * 16 + r;
    int xb = tx * 16 + ch * 8;
    #pragma unroll
    for (int oi = 0; oi < 8; ++oi) {
        int o = og * 8 + oi;
        float bo = bias[o];
        float v[8];
        #pragma unroll
        for (int j = 0; j < 8; ++j) {
            float a = acc[oi][j] + bo;
            v[j] = act ? LRELU(a) : a;
        }
        float* op = out + ((size_t)o * Hout + y) * Wout + xb;
        *(float4*)op       = make_float4(v[0], v[1], v[2], v[3]);
        *(float4*)(op + 4) = make_float4(v[4], v[5], v[6], v[7]);
    }
}

// ======== implicit-GEMM 3x3 conv, C=64 -> O=64, stride1 pad1, 16x8 tile (4px x 8och) ========
__global__ void conv64_gemm16x8(const float* __restrict__ in, const float* __restrict__ Wt,
                                const float* __restrict__ bias, float* __restrict__ out,
                                int H, int W, int act, int tilesX,
                                long long inStr, long long wStr, long long bStr, long long outStr)
{
    constexpr int CC = 8, TIN = 18, RS = 20;   // 10 rows x 18 cols window
    __shared__ float it[CC * 10 * RS];
    __shared__ float wl[CC * 9 * 64];
    int s = blockIdx.y;
    in   += (size_t)s * inStr;
    Wt   += (size_t)s * wStr;
    bias += (size_t)s * bStr;
    out  += (size_t)s * outStr;

    int b  = blockIdx.x;
    int tx = b % tilesX, ty = b / tilesX;
    int t  = threadIdx.x;
    int og = t >> 5, pg = t & 31;
    int r  = pg >> 2, ch = pg & 3;

    float acc[8][4];
    #pragma unroll
    for (int i = 0; i < 8; ++i)
        #pragma unroll
        for (int j = 0; j < 4; ++j) acc[i][j] = 0.f;

    const int y0 = ty * 8 - 1, x0 = tx * 16 - 1;
    const size_t plane = (size_t)H * W;

    for (int c0 = 0; c0 < 64; c0 += CC) {
        __syncthreads();
        {
            const float4* src = (const float4*)(Wt + c0 * 9 * 64);
            float4* dst = (float4*)wl;
            for (int i = t; i < CC * 9 * 16; i += 256) dst[i] = src[i];
        }
        for (int rowi = t; rowi < CC * 10; rowi += 256) {
            int cc = rowi / 10, rr = rowi - cc * 10;
            int iy = y0 + rr;
            float* dst = it + rowi * RS;
            const float* srow = in + (size_t)(c0 + cc) * plane + (size_t)iy * W + x0;
            if ((unsigned)iy < (unsigned)H && x0 >= 0 && x0 + RS <= W) {
                #pragma unroll
                for (int q = 0; q < 5; ++q)
                    ((float4*)dst)[q] = ((const float4*)srow)[q];
            } else {
                for (int cl = 0; cl < RS; ++cl) {
                    int ix = x0 + cl;
                    float v = 0.f;
                    if (cl < TIN && (unsigned)iy < (unsigned)H && (unsigned)ix < (unsigned)W)
                        v = in[(size_t)(c0 + cc) * plane + (size_t)iy * W + ix];
                    dst[cl] = v;
                }
            }
        }
        __syncthreads();
        for (int cc = 0; cc < CC; ++cc) {
            const float* base = it + cc * 10 * RS;
            #pragma unroll
            for (int ky = 0; ky < 3; ++ky) {
                const float* rowp = base + (r + ky) * RS + ch * 4;
                float4 f0 = *(const float4*)rowp;
                float4 f1 = *(const float4*)(rowp + 4);
                float p[8] = {f0.x, f0.y, f0.z, f0.w, f1.x, f1.y, f1.z, f1.w};
                #pragma unroll
                for (int kx = 0; kx < 3; ++kx) {
                    const float* wp = wl + ((cc * 9) + ky * 3 + kx) * 64 + og * 8;
                    float4 wa = *(const float4*)wp;
                    float4 wb = *(const float4*)(wp + 4);
                    float w8[8] = {wa.x, wa.y, wa.z, wa.w, wb.x, wb.y, wb.z, wb.w};
                    #pragma unroll
                    for (int oi = 0; oi < 8; ++oi)
                        #pragma unroll
                        for (int j = 0; j < 4; ++j)
                            acc[oi][j] += w8[oi] * p[j + kx];
                }
            }
        }
    }

    int y = ty * 8 + r, xb = tx * 16 + ch * 4;
    #pragma unroll
    for (int oi = 0; oi < 8; ++oi) {
        int o = og * 8 + oi;
        float bo = bias[o];
        float v0 = acc[oi][0] + bo, v1 = acc[oi][1] + bo;
        float v2 = acc[oi][2] + bo, v3 = acc[oi][3] + bo;
        if (act) { v0 = LRELU(v0); v1 = LRELU(v1); v2 = LRELU(v2); v3 = LRELU(v3); }
        *(float4*)(out + ((size_t)o * H + y) * W + xb) = make_float4(v0, v1, v2, v3);
    }
}

// ======== implicit-GEMM 3x3 conv, C=64 -> O=64, stride2, 16x8 out tile (4px x 8och) ========
__global__ void conv64s2_gemm16x8(const float* __restrict__ in, const float* __restrict__ Wt,
                                  const float* __restrict__ bias, float* __restrict__ out,
                                  int Hin, int Win, int Hout, int Wout, int pad, int act, int tilesX,
                                  long long inStr, long long wStr, long long bStr, long long outStr)
{
    constexpr int CC = 8, TIN = 35, RS = 36;   // 18 rows x 35 cols window
    __shared__ float it[CC * 18 * RS];
    __shared__ float wl[CC * 9 * 64];
    int s = blockIdx.y;
    in   += (size_t)s * inStr;
    Wt   += (size_t)s * wStr;
    bias += (size_t)s * bStr;
    out  += (size_t)s * outStr;

    int b  = blockIdx.x;
    int tx = b % tilesX, ty = b / tilesX;
    int t  = threadIdx.x;
    int og = t >> 5, pg = t & 31;
    int r  = pg >> 2, ch = pg & 3;

    float acc[8][4];
    #pragma unroll
    for (int i = 0; i < 8; ++i)
        #pragma unroll
        for (int j = 0; j < 4; ++j) acc[i][j] = 0.f;

    const int y0 = 2 * (ty * 8) - pad, x0 = 2 * (tx * 16) - pad;
    const size_t plane = (size_t)Hin * Win;

    for (int c0 = 0; c0 < 64; c0 += CC) {
        __syncthreads();
        {
            const float4* src = (const float4*)(Wt + c0 * 9 * 64);
            float4* dst = (float4*)wl;
            for (int i = t; i < CC * 9 * 16; i += 256) dst[i] = src[i];
        }
        for (int rowi = t; rowi < CC * 18; rowi += 256) {
            int cc = rowi / 18, rr = rowi - cc * 18;
            int iy = y0 + rr;
            float* dst = it + rowi * RS;
            const float* srow = in + (size_t)(c0 + cc) * plane + (size_t)iy * Win + x0;
            if ((unsigned)iy < (unsigned)Hin && x0 >= 0 && x0 + RS <= Win) {
                #pragma unroll
                for (int q = 0; q < 9; ++q)
                    ((float4*)dst)[q] = ((const float4*)srow)[q];
            } else {
                for (int cl = 0; cl < RS; ++cl) {
                    int ix = x0 + cl;
                    float v = 0.f;
                    if (cl < TIN && (unsigned)iy < (unsigned)Hin && (unsigned)ix < (unsigned)Win)
                        v = in[(size_t)(c0 + cc) * plane + (size_t)iy * Win + ix];
                    dst[cl] = v;
                }
            }
        }
        __syncthreads();
        for (int cc = 0; cc < CC; ++cc) {
            const float* base = it + cc * 18 * RS;
            #pragma unroll
            for (int ky = 0; ky < 3; ++ky) {
                const float* rowp = base + (2 * r + ky) * RS + ch * 8;
                float4 f0 = *(const float4*)rowp;
                float4 f1 = *(const float4*)(rowp + 4);
                float4 f2 = *(const float4*)(rowp + 8);
                float p[12] = {f0.x, f0.y, f0.z, f0.w, f1.x, f1.y, f1.z, f1.w,
                               f2.x, f2.y, f2.z, f2.w};
                #pragma unroll
                for (int kx = 0; kx < 3; ++kx) {
                    const float* wp = wl + ((cc * 9) + ky * 3 + kx) * 64 + og * 8;
                    float4 wa = *(const float4*)wp;
                    float4 wb = *(const float4*)(wp + 4);
                    float w8[8] = {wa.x, wa.y, wa.z, wa.w, wb.x, wb.y, wb.z, wb.w};
                    #pragma unroll
                    for (int oi = 0; oi < 8; ++oi)
                        #pragma unroll
                        for (int j = 0; j < 4; ++j)
                            acc[oi][j] += w8[oi] * p[2 * j + kx];
                }
            }
        }
    }

    int y = ty * 8 + r, xb = tx * 16 + ch * 4;
    #pragma unroll
    for (int oi = 0; oi < 8; ++oi) {
        int o = og * 8 + oi;
        float bo = bias[o];
        float v0 = acc[oi][0] + bo, v1 = acc[oi][1] + bo;
        float v2 = acc[oi][2] + bo, v3 = acc[oi][3] + bo;
        if (act) { v0 = LRELU(v0); v1 = LRELU(v1); v2 = LRELU(v2); v3 = LRELU(v3); }
        *(float4*)(out + ((size_t)o * Hout + y) * Wout + xb) = make_float4(v0, v1, v2, v3);
    }
}

// ======== implicit-GEMM 3x3 conv, C=64 -> O=64, stride1 pad1, 8x8 tile ========
__global__ void conv64_gemm8(const float* __restrict__ in, const float* __restrict__ Wt,
                             const float* __restrict__ bias, float* __restrict__ out,
                             int H, int W, int act, int tilesX,
                             long long inStr, long long wStr, long long bStr, long long outStr)
{
    constexpr int CC = 8, TIN = 10, RS = 12;
    __shared__ float it[CC * TIN * RS];
    __shared__ float wl[CC * 9 * 64];
    int s = blockIdx.y;
    in   += (size_t)s * inStr;
    Wt   += (size_t)s * wStr;
    bias += (size_t)s * bStr;
    out  += (size_t)s * outStr;

    int b  = blockIdx.x;
    int tx = b % tilesX, ty = b / tilesX;
    int t  = threadIdx.x;
    int og = t >> 5, pg = t & 31;
    int r  = pg >> 2, ch = pg & 3;

    float acc[8][2];
    #pragma unroll
    for (int i = 0; i < 8; ++i) { acc[i][0] = 0.f; acc[i][1] = 0.f; }

    const int y0 = ty * 8 - 1, x0 = tx * 8 - 1;
    const size_t plane = (size_t)H * W;

    for (int c0 = 0; c0 < 64; c0 += CC) {
        __syncthreads();
        {
            const float4* src = (const float4*)(Wt + c0 * 9 * 64);
            float4* dst = (float4*)wl;
            for (int i = t; i < CC * 9 * 16; i += 256) dst[i] = src[i];
        }
        for (int rowi = t; rowi < CC * TIN; rowi += 256) {
            int cc = rowi / TIN, rr = rowi - cc * TIN;
            int iy = y0 + rr;
            float* dst = it + rowi * RS;
            const float* srow = in + (size_t)(c0 + cc) * plane + (size_t)iy * W + x0;
            if ((unsigned)iy < (unsigned)H && x0 >= 0 && x0 + RS <= W) {
                #pragma unroll
                for (int q = 0; q < 3; ++q)
                    ((float4*)dst)[q] = ((const float4*)srow)[q];
            } else {
                for (int cl = 0; cl < RS; ++cl) {
                    int ix = x0 + cl;
                    float v = 0.f;
                    if (cl < TIN && (unsigned)iy < (unsigned)H && (unsigned)ix < (unsigned)W)
                        v = in[(size_t)(c0 + cc) * plane + (size_t)iy * W + ix];
                    dst[cl] = v;
                }
            }
        }
        __syncthreads();
        for (int cc = 0; cc < CC; ++cc) {
            const float* base = it + cc * TIN * RS;
            #pragma unroll
            for (int ky = 0; ky < 3; ++ky) {
                const float* rowp = base + (r + ky) * RS + ch * 2;
                float p[4] = {rowp[0], rowp[1], rowp[2], rowp[3]};
                #pragma unroll
                for (int kx = 0; kx < 3; ++kx) {
                    const float* wp = wl + ((cc * 9) + ky * 3 + kx) * 64 + og * 8;
                    float4 wa = *(const float4*)wp;
                    float4 wb = *(const float4*)(wp + 4);
                    float w8[8] = {wa.x, wa.y, wa.z, wa.w, wb.x, wb.y, wb.z, wb.w};
                    #pragma unroll
                    for (int oi = 0; oi < 8; ++oi) {
                        acc[oi][0] += w8[oi] * p[kx];
                        acc[oi][1] += w8[oi] * p[kx + 1];
                    }
                }
            }
        }
    }

    int y = ty * 8 + r, xb = tx * 8 + ch * 2;
    #pragma unroll
    for (int oi = 0; oi < 8; ++oi) {
        int o = og * 8 + oi;
        float bo = bias[o];
        float a0 = acc[oi][0] + bo, a1 = acc[oi][1] + bo;
        if (act) { a0 = LRELU(a0); a1 = LRELU(a1); }
        *(float2*)(out + ((size_t)o * H + y) * W + xb) = make_float2(a0, a1);
    }
}

// ======== implicit-GEMM 3x3 conv, C=64 -> O=64, stride2, 8x8 out tile ========
__global__ void conv64s2_gemm8(const float* __restrict__ in, const float* __restrict__ Wt,
                               const float* __restrict__ bias, float* __restrict__ out,
                               int Hin, int Win, int Hout, int Wout, int pad, int act, int tilesX,
                               long long inStr, long long wStr, long long bStr, long long outStr)
{
    constexpr int CC = 8, TIN = 18, RS = 20;
    __shared__ float it[CC * TIN * RS];
    __shared__ float wl[CC * 9 * 64];
    int s = blockIdx.y;
    in   += (size_t)s * inStr;
    Wt   += (size_t)s * wStr;
    bias += (size_t)s * bStr;
    out  += (size_t)s * outStr;

    int b  = blockIdx.x;
    int tx = b % tilesX, ty = b / tilesX;
    int t  = threadIdx.x;
    int og = t >> 5, pg = t & 31;
    int r  = pg >> 2, ch = pg & 3;

    float acc[8][2];
    #pragma unroll
    for (int i = 0; i < 8; ++i) { acc[i][0] = 0.f; acc[i][1] = 0.f; }

    const int y0 = ty * 16 - pad, x0 = tx * 16 - pad;
    const size_t plane = (size_t)Hin * Win;

    for (int c0 = 0; c0 < 64; c0 += CC) {
        __syncthreads();
        {
            const float4* src = (const float4*)(Wt + c0 * 9 * 64);
            float4* dst = (float4*)wl;
            for (int i = t; i < CC * 9 * 16; i += 256) dst[i] = src[i];
        }
        for (int rowi = t; rowi < CC * TIN; rowi += 256) {
            int cc = rowi / TIN, rr = rowi - cc * TIN;
            int iy = y0 + rr;
            float* dst = it + rowi * RS;
            const float* srow = in + (size_t)(c0 + cc) * plane + (size_t)iy * Win + x0;
            if ((unsigned)iy < (unsigned)Hin && x0 >= 0 && x0 + RS <= Win) {
                #pragma unroll
                for (int q = 0; q < RS / 4; ++q)
                    ((float4*)dst)[q] = ((const float4*)srow)[q];
            } else {
                for (int cl = 0; cl < RS; ++cl) {
                    int ix = x0 + cl;
                    float v = 0.f;
                    if (cl < TIN && (unsigned)iy < (unsigned)Hin && (unsigned)ix < (unsigned)Win)
                        v = in[(size_t)(c0 + cc) * plane + (size_t)iy * Win + ix];
                    dst[cl] = v;
                }
            }
        }
        __syncthreads();
        for (int cc = 0; cc < CC; ++cc) {
            const float* base = it + cc * TIN * RS;
            #pragma unroll
            for (int ky = 0; ky < 3; ++ky) {
                const float* rowp = base + (2 * r + ky) * RS + ch * 4;
                float4 f0 = *(const float4*)rowp;
                float4 f1 = *(const float4*)(rowp + 4);
                float p[8] = {f0.x, f0.y, f0.z, f0.w, f1.x, f1.y, f1.z, f1.w};
                #pragma unroll
                for (int kx = 0; kx < 3; ++kx) {
                    const float* wp = wl + ((cc * 9) + ky * 3 + kx) * 64 + og * 8;
                    float4 wa = *(const float4*)wp;
                    float4 wb = *(const float4*)(wp + 4);
                    float w8[8] = {wa.x, wa.y, wa.z, wa.w, wb.x, wb.y, wb.z, wb.w};
                    #pragma unroll
                    for (int oi = 0; oi < 8; ++oi) {
                        acc[oi][0] += w8[oi] * p[kx];
                        acc[oi][1] += w8[oi] * p[kx + 2];
                    }
                }
            }
        }
    }

    int y = ty * 8 + r, xb = tx * 8 + ch * 2;
    #pragma unroll
    for (int oi = 0; oi < 8; ++oi) {
        int o = og * 8 + oi;
        float bo = bias[o];
        float a0 = acc[oi][0] + bo, a1 = acc[oi][1] + bo;
        if (act) { a0 = LRELU(a0); a1 = LRELU(a1); }
        *(float2*)(out + ((size_t)o * Hout + y) * Wout + xb) = make_float2(a0, a1);
    }
}

// ========== implicit-GEMM 3x3 conv, C=3 -> O=64, stride1 pad1 (g0 guide, f0) ==========
__global__ void conv3_gemm(const float* __restrict__ in, const float* __restrict__ Wt,
                           const float* __restrict__ bias, float* __restrict__ out,
                           int H, int W, int tilesX,
                           long long inStr, long long wStr, long long bStr, long long outStr)
{
    constexpr int TIN = 18, RS = 20;
    __shared__ float it[3 * TIN * RS];
    __shared__ float wl[27 * 64];
    int s = blockIdx.y;
    in   += (size_t)s * inStr;
    Wt   += (size_t)s * wStr;
    bias += (size_t)s * bStr;
    out  += (size_t)s * outStr;

    int b  = blockIdx.x;
    int tx = b % tilesX, ty = b / tilesX;
    int t  = threadIdx.x;
    {
        const float4* src = (const float4*)Wt;
        float4* dst = (float4*)wl;
        for (int i = t; i < 27 * 16; i += 256) dst[i] = src[i];
    }
    const int y0 = ty * 16 - 1, x0 = tx * 16 - 1;
    const size_t plane = (size_t)H * W;
    for (int rowi = t; rowi < 3 * TIN; rowi += 256) {
        int cc = rowi / TIN, rr = rowi - cc * TIN;
        int iy = y0 + rr;
        float* dst = it + (size_t)rowi * RS;
        const float* srow = in + (size_t)cc * plane + (size_t)iy * W + x0;
        if ((unsigned)iy < (unsigned)H && x0 >= 0 && x0 + RS <= W) {
            #pragma unroll
            for (int q = 0; q < RS / 4; ++q)
                ((float4*)dst)[q] = ((const float4*)srow)[q];
        } else {
            for (int cl = 0; cl < TIN; ++cl) {
                int ix = x0 + cl;
                float v = 0.f;
                if ((unsigned)iy < (unsigned)H && (unsigned)ix < (unsigned)W)
                    v = in[(size_t)cc * plane + (size_t)iy * W + ix];
                dst[cl] = v;
            }
        }
    }
    __syncthreads();

    int og = t >> 5, pg = t & 31;
    int r  = pg >> 1, ch = pg & 1;
    float acc[8][8];
    #pragma unroll
    for (int i = 0; i < 8; ++i)
        #pragma unroll
        for (int j = 0; j < 8; ++j) acc[i][j] = 0.f;

    for (int c = 0; c < 3; ++c) {
        const float* base = it + c * TIN * RS;
        #pragma unroll
        for (int ky = 0; ky < 3; ++ky) {
            float p[12];
            const float* rowp = base + (r + ky) * RS + ch * 8;
            #pragma unroll
            for (int q = 0; q < 3; ++q) {
                float4 f = *(const float4*)(rowp + q * 4);
                p[q*4+0] = f.x; p[q*4+1] = f.y; p[q*4+2] = f.z; p[q*4+3] = f.w;
            }
            #pragma unroll
            for (int kx = 0; kx < 3; ++kx) {
                const float* wp = wl + ((c * 9) + ky * 3 + kx) * 64 + og * 8;
                float4 wa = *(const float4*)wp;
                float4 wb = *(const float4*)(wp + 4);
                float w8[8] = {wa.x, wa.y, wa.z, wa.w, wb.x, wb.y, wb.z, wb.w};
                #pragma unroll
                for (int oi = 0; oi < 8; ++oi)
                    #pragma unroll
                    for (int j = 0; j < 8; ++j)
                        acc[oi][j] += w8[oi] * p[j + kx];
            }
        }
    }

    int y  = ty * 16 + r;
    int xb = tx * 16 + ch * 8;
    #pragma unroll
    for (int oi = 0; oi < 8; ++oi) {
        int o = og * 8 + oi;
        float bo = bias[o];
        float v[8];
        #pragma unroll
        for (int j = 0; j < 8; ++j) {
            float a = acc[oi][j] + bo;
            v[j] = LRELU(a);
        }
        float* op = out + ((size_t)o * H + y) * W + xb;
        *(float4*)op       = make_float4(v[0], v[1], v[2], v[3]);
        *(float4*)(op + 4) = make_float4(v[4], v[5], v[6], v[7]);
    }
}

// ========== implicit-GEMM 3x3 conv, C=64 -> O=3, (in1+in2), no act (c6) ==========
__global__ void conv64to3_gemm(const float* __restrict__ in, const float* __restrict__ in2,
                               const float* __restrict__ Wt, const float* __restrict__ sb,
                               float* __restrict__ out, int H, int W, int tilesX,
                               long long inStr, long long wStr, long long sbStr, long long outStr)
{
    constexpr int CC = 8, TIN = 18, RS = 20;
    __shared__ float it[CC * TIN * RS];
    __shared__ float wl[CC * 9 * 3];
    int s = blockIdx.y;
    in  += (size_t)s * inStr;
    in2 += (size_t)s * inStr;
    Wt  += (size_t)s * wStr;
    sb  += (size_t)s * sbStr;
    out += (size_t)s * outStr;

    int b  = blockIdx.x;
    int tx = b % tilesX, ty = b / tilesX;
    int t  = threadIdx.x;
    int r  = t >> 4, cl = t & 15;
    const int y0 = ty * 16 - 1, x0 = tx * 16 - 1;
    const size_t plane = (size_t)H * W;

    float acc[3] = {0.f, 0.f, 0.f};

    for (int c0 = 0; c0 < 64; c0 += CC) {
        __syncthreads();
        for (int i = t; i < CC * 9 * 3; i += 256) wl[i] = Wt[c0 * 27 + i];
        for (int rowi = t; rowi < CC * TIN; rowi += 256) {
            int cc = rowi / TIN, rr = rowi - cc * TIN;
            int iy = y0 + rr;
            float* dst = it + (size_t)rowi * RS;
            size_t roff = (size_t)(c0 + cc) * plane + (size_t)iy * W + x0;
            if ((unsigned)iy < (unsigned)H && x0 >= 0 && x0 + RS <= W) {
                #pragma unroll
                for (int q = 0; q < RS / 4; ++q) {
                    float4 a = ((const float4*)(in  + roff))[q];
                    float4 bb = ((const float4*)(in2 + roff))[q];
                    ((float4*)dst)[q] = make_float4(a.x + bb.x, a.y + bb.y, a.z + bb.z, a.w + bb.w);
                }
            } else {
                for (int c2 = 0; c2 < TIN; ++c2) {
                    int ix = x0 + c2;
                    float v = 0.f;
                    if ((unsigned)iy < (unsigned)H && (unsigned)ix < (unsigned)W) {
                        size_t off = (size_t)(c0 + cc) * plane + (size_t)iy * W + ix;
                        v = in[off] + in2[off];
                    }
                    dst[c2] = v;
                }
            }
        }
        __syncthreads();
        for (int cc = 0; cc < CC; ++cc) {
            const float* base = it + cc * TIN * RS;
            #pragma unroll
            for (int ky = 0; ky < 3; ++ky) {
                const float* rowp = base + (r + ky) * RS + cl;
                float p0 = rowp[0], p1 = rowp[1], p2 = rowp[2];
                const float* wr = wl + (cc * 9 + ky * 3) * 3;
                #pragma unroll
                for (int o = 0; o < 3; ++o)
                    acc[o] += wr[o] * p0 + wr[3 + o] * p1 + wr[6 + o] * p2;
            }
        }
    }

    int y = ty * 16 + r, x = tx * 16 + cl;
    #pragma unroll
    for (int o = 0; o < 3; ++o)
        out[((size_t)o * H + y) * W + x] = acc[o] + sb[o];
}

// ===== fused up-conv: tconv(s2,3x3)+blur(4x4,x4/64)+bias+lrelu, 32x8 tile, LDS-staged stores =====
// Round-14 proven config: lane map t = og[0:2]|pxb[3]|xh[4]|r[5:7], PSTR=68, separate ost.
__global__ void upconv64_gemm(const float* __restrict__ in, const float* __restrict__ in2,
                              const float* __restrict__ G2, const float* __restrict__ sb,
                              float* __restrict__ out, int Hin, int Win, int tilesX,
                              long long bufStr, long long sbStr, long long outStr)
{
    constexpr int CC = 4;
    constexpr int RS = 20;                    // 18-col window, padded
    constexpr int PSTR = 68;                  // padded parity stride (floats)
    extern __shared__ float lds[];
    float* it  = lds;                         // [CC][6][RS] = 480
    float* wl  = lds + CC * 6 * RS;           // [CC][9][4][PSTR] = CC*2448
    float* ost = wl + CC * 2448;              // [64][33] = 2112

    int s = blockIdx.y;
    in  += (size_t)s * bufStr;
    in2 += (size_t)s * bufStr;
    G2  += (size_t)s * bufStr;
    sb  += (size_t)s * sbStr;
    out += (size_t)s * outStr;

    int b  = blockIdx.x;
    int tx = b % tilesX, ty = b / tilesX;
    int t  = threadIdx.x;
    int og  = t & 7;
    int pxb = (t >> 3) & 1;
    int xh  = (t >> 4) & 1;
    int r   = t >> 5;                         // out row 0..7
    int rhalf = r >> 1, rpar = r & 1;
    const int Y0 = ty * 8, X0 = tx * 32;
    const int gy0 = Y0 / 2 - 1;
    const int gx0 = X0 / 2 - 1;
    const size_t plane = (size_t)Hin * Win;

    float acc[8][8];
    #pragma unroll
    for (int i = 0; i < 8; ++i)
        #pragma unroll
        for (int j = 0; j < 8; ++j) acc[i][j] = 0.f;

    for (int c0 = 0; c0 < 64; c0 += CC) {
        __syncthreads();
        {
            const float4* src = (const float4*)(G2 + (size_t)c0 * 2304);
            for (int i = t; i < CC * 36 * 16; i += 256) {
                int row = i >> 4, q = i & 15;
                ((float4*)(wl + row * PSTR))[q] = src[i];
            }
        }
        for (int rowi = t; rowi < CC * 6; rowi += 256) {
            int cc = rowi / 6, rr = rowi - cc * 6;
            int gi = gy0 + rr;
            float* dst = it + (size_t)rowi * RS;
            size_t roff = (size_t)(c0 + cc) * plane + (size_t)gi * Win + gx0;
            if ((unsigned)gi < (unsigned)Hin && gx0 >= 0 && gx0 + RS <= Win) {
                #pragma unroll
                for (int qq = 0; qq < 5; ++qq) {
                    float4 a = ((const float4*)(in  + roff))[qq];
                    float4 bb = ((const float4*)(in2 + roff))[qq];
                    ((float4*)dst)[qq] = make_float4(a.x + bb.x, a.y + bb.y, a.z + bb.z, a.w + bb.w);
                }
            } else {
                for (int cl = 0; cl < RS; ++cl) {
                    int gj = gx0 + cl;
                    float v = 0.f;
                    if (cl < 18 && (unsigned)gi < (unsigned)Hin && (unsigned)gj < (unsigned)Win) {
                        size_t off = (size_t)(c0 + cc) * plane + (size_t)gi * Win + gj;
                        v = in[off] + in2[off];
                    }
                    dst[cl] = v;
                }
            }
        }
        __syncthreads();
        for (int cc = 0; cc < CC; ++cc) {
            const float* ib = it + cc * 6 * RS;
            const float* wcb = wl + cc * (36 * PSTR) + (rpar * 2 + pxb) * PSTR;
            #pragma unroll
            for (int ty2 = 0; ty2 < 3; ++ty2) {
                float p[12];
                const float* rowp = ib + (rhalf + ty2) * RS + xh * 8;
                #pragma unroll
                for (int qq = 0; qq < 3; ++qq) {
                    float4 f = *(const float4*)(rowp + qq * 4);
                    p[qq*4+0] = f.x; p[qq*4+1] = f.y; p[qq*4+2] = f.z; p[qq*4+3] = f.w;
                }
                #pragma unroll
                for (int tx2 = 0; tx2 < 3; ++tx2) {
                    const float* wp = wcb + (ty2 * 3 + tx2) * (4 * PSTR) + og * 8;
                    float4 wa = *(const float4*)wp;
                    float4 wv = *(const float4*)(wp + 4);
                    float w8[8] = {wa.x, wa.y, wa.z, wa.w, wv.x, wv.y, wv.z, wv.w};
                    #pragma unroll
                    for (int oi = 0; oi < 8; ++oi)
                        #pragma unroll
                        for (int k = 0; k < 8; ++k)
                            acc[oi][k] += w8[oi] * p[k + tx2];
                }
            }
        }
    }

    const int Hout = 2 * Hin, Wout = 2 * Win;
    const int obase = (r * 8 + og) * 33 + xh * 16 + pxb;
    #pragma unroll
    for (int oi = 0; oi < 8; ++oi) {
        int o = og * 8 + oi;
        float bo = sb[o];
        __syncthreads();
        #pragma unroll
        for (int k = 0; k < 8; ++k) {
            float a = acc[oi][k] + bo;
            ost[obase + 2 * k] = LRELU(a);
        }
        __syncthreads();
        #pragma unroll
        for (int p2 = 0; p2 < 2; ++p2) {
            int j4 = p2 * 256 + t;
            int ogr = j4 >> 6;
            int rr  = (j4 >> 3) & 7;
            int x4  = j4 & 7;
            const float* sp = ost + (rr * 8 + ogr) * 33 + x4 * 4;
            float4 f = make_float4(sp[0], sp[1], sp[2], sp[3]);
            int oo = ogr * 8 + oi;
            *(float4*)(out + ((size_t)oo * Hout + Y0 + rr) * Wout + X0 + x4 * 4) = f;
        }
    }
}

// ------- build combined up-weights, layout [c][tap][parity][o] -------
__global__ void combine_up_w(const float* __restrict__ W, float* __restrict__ G2,
                             long long wStr, long long g2Str)
{
    int s = blockIdx.y;
    W  += (size_t)s * wStr;
    G2 += (size_t)s * g2Str;
    int i = blockIdx.x * 256 + threadIdx.x;
    if (i >= 147456) return;
    int o = i & 63;
    int rest = i >> 6;
    int p4 = rest & 3;
    int k9 = (rest >> 2) % 9;
    int c  = (rest >> 2) / 9;
    int py = p4 >> 1, px = p4 & 1;
    int tyk = k9 / 3, txk = k9 % 3;
    int dy = 2 * tyk - 1 - py, dx = 2 * txk - 1 - px;
    const float K[4] = {1.f, 3.f, 3.f, 1.f};
    const float* wp = W + ((size_t)o * 64 + c) * 9;
    float sacc = 0.f;
    #pragma unroll
    for (int a = 0; a < 3; ++a) {
        int ky = a + dy;
        if ((unsigned)ky >= 4u) continue;
        #pragma unroll
        for (int b2 = 0; b2 < 3; ++b2) {
            int kx = b2 + dx;
            if ((unsigned)kx >= 4u) continue;
            sacc += K[ky] * K[kx] * wp[a * 3 + b2];
        }
    }
    G2[i] = sacc * (1.f / 16.f);
}

// ---------------- 4x4 blur pad=2 (pre-down), batched ----------------
__global__ void blur_down(const float* __restrict__ in, float* __restrict__ out,
                          int H, int W, int tilesX, int tilesY,
                          long long inStr, long long outStr)
{
    int s = blockIdx.y;
    in  += (size_t)s * inStr;
    out += (size_t)s * outStr;
    int Ho = H + 1, Wo = W + 1;
    int bid = blockIdx.x;
    int tx = bid % tilesX; bid /= tilesX;
    int ty = bid % tilesY; bid /= tilesY;
    int p  = bid;
    int x = tx * 16 + (threadIdx.x & 15);
    int y = ty * 16 + (threadIdx.x >> 4);
    if (x >= Wo || y >= Ho) return;
    const float k[4] = {1.f, 3.f, 3.f, 1.f};
    const float* ip = in + (size_t)p * H * W;
    float acc = 0.f;
    #pragma unroll
    for (int ky = 0; ky < 4; ++ky) {
        int iy = y - 2 + ky;
        if ((unsigned)iy >= (unsigned)H) continue;
        float row = 0.f;
        #pragma unroll
        for (int kx = 0; kx < 4; ++kx) {
            int ix = x - 2 + kx;
            if ((unsigned)ix >= (unsigned)W) continue;
            row += ip[(size_t)iy * W + ix] * k[kx];
        }
        acc += row * k[ky];
    }
    out[((size_t)p * Ho + y) * Wo + x] = acc * (1.f / 64.f);
}

// ---------------- avg pool to 1x1 (64 planes), batched ----------------
__global__ void avgpool_hw(const float* __restrict__ in, float* __restrict__ out, int HW,
                           long long inStr, long long outStr)
{
    int s = blockIdx.y;
    in  += (size_t)s * inStr;
    out += (size_t)s * outStr;
    int p = blockIdx.x;
    const float* ip = in + (size_t)p * HW;
    float sum = 0.f;
    for (int i = threadIdx.x; i < HW; i += blockDim.x) sum += ip[i];
    __shared__ float red[256];
    red[threadIdx.x] = sum;
    __syncthreads();
    for (int off = 128; off; off >>= 1) {
        if ((int)threadIdx.x < off) red[threadIdx.x] += red[threadIdx.x + off];
        __syncthreads();
    }
    if (threadIdx.x == 0) out[p] = red[0] / (float)HW;
}

// ---------------- style FC (single layer) ----------------
__global__ void style_fc(const float* __restrict__ s, const float* __restrict__ W,
                         const float* __restrict__ b, float* __restrict__ out, int outdim)
{
    int n = blockIdx.x;
    int i = threadIdx.x;
    if (i >= outdim) return;
    float acc = b[i];
    const float* sn = s + n * 64;
    const float* wi = W + i * 64;
    for (int f = 0; f < 64; ++f) acc += sn[f] * wi[f];
    out[n * 64 + i] = LRELU(acc);
}

// ------- merged style FC for the 10 mid layers: grid (8 samples, 10 layers, 2 sw/sb) -------
__global__ void style_fc_mids(const float* __restrict__ s,
                              const float* __restrict__ midswW, const float* __restrict__ midswb,
                              const float* __restrict__ midsbW, const float* __restrict__ midsbb,
                              float* __restrict__ sty)
{
    int n = blockIdx.x, li = blockIdx.y, z = blockIdx.z;
    const float* W = (z ? midsbW : midswW) + (size_t)li * 4096;
    const float* b = (z ? midsbb : midswb) + (size_t)li * 64;
    float* out = sty + (size_t)(1 + li) * 1024 + z * 512;
    int i = threadIdx.x;
    float acc = b[i];
    const float* sn = s + n * 64;
    const float* wi = W + i * 64;
    for (int f = 0; f < 64; ++f) acc += sn[f] * wi[f];
    out[n * 64 + i] = LRELU(acc);
}

// ------- modulate+demodulate (single layer, all 8 samples); transpose=1 -> [c][k][o] -------
__global__ void modulate(const float* __restrict__ w, const float* __restrict__ sw,
                         float* __restrict__ wout, int O, int C, int transpose)
{
    int no = blockIdx.x;
    int o = no % O, n = no / O;
    int nw = C * 9;
    int t = threadIdx.x;
    float v[9];
    int cnt = 0;
    float ss = 0.f;
    for (int idx = t; idx < nw; idx += 64) {
        int c = idx / 9;
        float val = w[o * nw + idx] * sw[n * 64 + c];
        v[cnt++] = val;
        ss += val * val;
    }
    #pragma unroll
    for (int off = 32; off; off >>= 1) ss += __shfl_xor(ss, off);
    float d = rsqrtf(ss + 1e-8f);
    cnt = 0;
    for (int idx = t; idx < nw; idx += 64) {
        float val = v[cnt++] * d;
        if (transpose)
            wout[(size_t)n * nw * O + (size_t)idx * O + o] = val;
        else
            wout[(size_t)no * nw + idx] = val;
    }
}

// ------- merged modulate for the 10 mid layers: grid (512, 10). trf=0 for li in {6,8} -------
__global__ void modulate_mids(const float* __restrict__ midw, const float* __restrict__ sty,
                              float* __restrict__ wmBase)
{
    int li = blockIdx.y;
    const float* w  = midw + (size_t)li * 36864;
    const float* sw = sty + (size_t)(1 + li) * 1024;
    float* wout = wmBase + (size_t)li * 294912;
    int transpose = !(li == 6 || li == 8);
    int no = blockIdx.x;
    int o = no & 63, n = no >> 6;
    int t = threadIdx.x;
    float v[9];
    int cnt = 0;
    float ss = 0.f;
    for (int idx = t; idx < 576; idx += 64) {
        int c = idx / 9;
        float val = w[o * 576 + idx] * sw[n * 64 + c];
        v[cnt++] = val;
        ss += val * val;
    }
    #pragma unroll
    for (int off = 32; off; off >>= 1) ss += __shfl_xor(ss, off);
    float d = rsqrtf(ss + 1e-8f);
    cnt = 0;
    for (int idx = t; idx < 576; idx += 64) {
        float val = v[cnt++] * d;
        if (transpose)
            wout[(size_t)n * 576 * 64 + (size_t)idx * 64 + o] = val;
        else
            wout[((size_t)n * 64 + o) * 576 + idx] = val;
    }
}

// ------- guide weight transpose -------
__global__ void guide_transpose(const float* __restrict__ grw, float* __restrict__ gt, int total)
{
    int i = blockIdx.x * 256 + threadIdx.x;
    if (i >= total) return;
    int l = i / 36864, rem = i % 36864;
    int idx = rem / 64, o = rem % 64;
    int c = idx / 9, k = idx % 9;
    gt[i] = grw[(((size_t)l * 64 + o) * 64 + c) * 9 + k];
}

// ------- g0 weight transpose -------
__global__ void g0_transpose(const float* __restrict__ g0w, float* __restrict__ gt)
{
    int i = blockIdx.x * 256 + threadIdx.x;
    if (i >= 1728) return;
    int idx = i / 64, o = i % 64;
    int c = idx / 9, k = idx % 9;
    gt[i] = g0w[((size_t)o * 3 + c) * 9 + k];
}

__global__ void fill_sentinel(float* __restrict__ out, int n)
{
    int i = blockIdx.x * 256 + threadIdx.x;
    if (i < n) out[i] = 1.0e9f;
}

extern "C" void kernel_launch(void* const* d_in, const int* in_sizes, int n_in,
                              void* d_out, int out_size, void* d_ws, size_t ws_size,
                              hipStream_t stream)
{
    const float* x     = (const float*)d_in[0];
    const float* ref   = (const float*)d_in[1];
    const float* g0w   = (const float*)d_in[2];
    const float* g0b   = (const float*)d_in[3];
    const float* grw   = (const float*)d_in[4];
    const float* grb   = (const float*)d_in[5];
    const float* c0w   = (const float*)d_in[6];
    const float* c0swW = (const float*)d_in[7];
    const float* c0swb = (const float*)d_in[8];
    const float* c0sbW = (const float*)d_in[9];
    const float* c0sbb = (const float*)d_in[10];
    const float* midw  = (const float*)d_in[11];
    const float* midswW= (const float*)d_in[12];
    const float* midswb= (const float*)d_in[13];
    const float* midsbW= (const float*)d_in[14];
    const float* midsbb= (const float*)d_in[15];
    const float* c6w   = (const float*)d_in[16];
    const float* c6swW = (const float*)d_in[17];
    const float* c6swb = (const float*)d_in[18];
    const float* c6sbW = (const float*)d_in[19];
    const float* c6sbb = (const float*)d_in[20];
    float* out = (float*)d_out;
    float* ws  = (float*)d_ws;

    // -------- shared region (floats) --------
    const size_t SV  = 0;
    const size_t STY = 512;
    const size_t WM  = 12800;
    const size_t GT  = 2989568;
    const size_t G0T = 3137024;
    const size_t BUF = 3138816;

    // -------- main-path per-sample slot offsets --------
    const size_t SA = 0;                  // [64,257,257]-class
    const size_t SB = 4227136;            // [64,256,256]
    const size_t D1 = 8421440;            // [64,128,128]
    const size_t D2 = 9470016;            // [64,128,128]
    const size_t D3 = 10518592;           // [64,129,129]-class
    const size_t E1 = 11583616;           // [64,64,64]
    const size_t E2 = 11845760;
    const size_t E3 = 12107904;
    const size_t G2o = 12370048;          // combined up-weights [147456]
    const long long PER = 12517504ll;     // ~50.1 MB per sample

    // -------- guide-phase per-sample slot offsets --------
    const size_t gSA = 0;
    const size_t gD1 = 4194304;
    const size_t gD2 = 5242880;
    const size_t gE1 = 6291456;
    const size_t gE2 = 6553600;
    const long long GPER = 6815744ll;

    int G = 0, GG = 0;
    for (int g = 8; g >= 1; --g)
        if ((BUF + (size_t)g * PER) * sizeof(float) <= ws_size) { G = g; break; }
    for (int g = 8; g >= 1; --g)
        if ((BUF + (size_t)g * GPER) * sizeof(float) <= ws_size) { GG = g; break; }
    if (!G || !GG) {
        fill_sentinel<<<dim3((out_size + 255) / 256), dim3(256), 0, stream>>>(out, out_size);
        return;
    }

    dim3 blk(256);
    const int LDS1 = 29952;
    const int LDSU = (4 * 6 * 20 + 4 * 2448 + 2112) * 4;   // 49536 B (round-14 proven)

    float* B = ws + BUF;

    guide_transpose<<<dim3(147456 / 256), blk, 0, stream>>>(grw, ws + GT, 147456);
    g0_transpose<<<dim3(7), blk, 0, stream>>>(g0w, ws + G0T);

    // ==================== guide net ====================
    for (int n0 = 0; n0 < 8; ) {
        int g = (8 - n0 < GG) ? (8 - n0) : GG;
        const float* refg = ref + (size_t)n0 * 196608;
        conv3_gemm<<<dim3(16 * 16, g), blk, 0, stream>>>(
            refg, ws + G0T, g0b, B + gSA, 256, 256, 16, 196608, 0, 0, GPER);
        conv64s2_gemm16x8<<<dim3(8 * 16, g), blk, 0, stream>>>(
            B + gSA, ws + GT, grb, B + gD1, 256, 256, 128, 128, 1, 1, 8, GPER, 0, 0, GPER);
        conv64_gemm16x8<<<dim3(8 * 16, g), blk, 0, stream>>>(
            B + gD1, ws + GT + 36864, grb + 64, B + gD2, 128, 128, 1, 8, GPER, 0, 0, GPER);
        conv64s2_gemm8<<<dim3(8 * 8, g), blk, 0, stream>>>(
            B + gD2, ws + GT + 73728, grb + 128, B + gE1, 128, 128, 64, 64, 1, 1, 8, GPER, 0, 0, GPER);
        conv64_gemm8<<<dim3(8 * 8, g), blk, 0, stream>>>(
            B + gE1, ws + GT + 110592, grb + 192, B + gE2, 64, 64, 0, 8, GPER, 0, 0, GPER);
        avgpool_hw<<<dim3(64, g), blk, 0, stream>>>(B + gE2, ws + SV + (size_t)n0 * 64, 4096, GPER, 64);
        n0 += g;
    }

    // ==================== styles + modulated weights ====================
    style_fc<<<dim3(8), dim3(64), 0, stream>>>(ws + SV, c0swW, c0swb, ws + STY + 0 * 1024, 3);
    style_fc<<<dim3(8), dim3(64), 0, stream>>>(ws + SV, c0sbW, c0sbb, ws + STY + 0 * 1024 + 512, 64);
    modulate<<<dim3(8 * 64), dim3(64), 0, stream>>>(c0w, ws + STY + 0 * 1024, ws + WM, 64, 3, 1);
    style_fc_mids<<<dim3(8, 10, 2), dim3(64), 0, stream>>>(
        ws + SV, midswW, midswb, midsbW, midsbb, ws + STY);
    modulate_mids<<<dim3(512, 10), dim3(64), 0, stream>>>(midw, ws + STY, ws + WM + 13824);
    style_fc<<<dim3(8), dim3(64), 0, stream>>>(ws + SV, c6swW, c6swb, ws + STY + 11 * 1024, 64);
    style_fc<<<dim3(8), dim3(64), 0, stream>>>(ws + SV, c6sbW, c6sbb, ws + STY + 11 * 1024 + 512, 3);
    modulate<<<dim3(8 * 3), dim3(64), 0, stream>>>(c6w, ws + STY + 11 * 1024, ws + WM + 13824 + 2949120, 3, 64, 1);

    size_t wmo[12];
    int Ci[12], Oi[12];
    wmo[0] = WM; Ci[0] = 3; Oi[0] = 64;
    for (int i = 0; i < 10; ++i) { wmo[1 + i] = WM + 13824ull + (size_t)i * 294912ull; Ci[1 + i] = 64; Oi[1 + i] = 64; }
    wmo[11] = WM + 13824ull + 2949120ull; Ci[11] = 64; Oi[11] = 3;

    // ==================== main path ====================
    for (int n0 = 0; n0 < 8; ) {
        int g = (8 - n0 < G) ? (8 - n0) : G;
        const float* xg = x + (size_t)n0 * 196608;
        float* outg = out + (size_t)n0 * 196608;
        #define WN(i)  (ws + wmo[i] + (size_t)n0 * Oi[i] * Ci[i] * 9)
        #define WSTR(i) ((long long)(Oi[i] * Ci[i] * 9))
        #define SBN(i) (ws + STY + (i) * 1024 + 512 + (size_t)n0 * 64)
        // f0 -> SB
        conv3_gemm<<<dim3(16 * 16, g), blk, 0, stream>>>(
            xg, WN(0), SBN(0), B + SB, 256, 256, 16, 196608, WSTR(0), 64, PER);
        // f1 down: blur(SB) -> SA; conv s2 -> D1; conv -> D2
        blur_down<<<dim3(64 * 17 * 17, g), blk, 0, stream>>>(B + SB, B + SA, 256, 256, 17, 17, PER, PER);
        conv64s2_gemm16x8<<<dim3(8 * 16, g), blk, 0, stream>>>(
            B + SA, WN(1), SBN(1), B + D1, 257, 257, 128, 128, 0, 1, 8, PER, WSTR(1), 64, PER);
        conv64_gemm16x8<<<dim3(8 * 16, g), blk, 0, stream>>>(
            B + D1, WN(2), SBN(2), B + D2, 128, 128, 1, 8, PER, WSTR(2), 64, PER);
        // f2 down
        blur_down<<<dim3(64 * 9 * 9, g), blk, 0, stream>>>(B + D2, B + D3, 128, 128, 9, 9, PER, PER);
        conv64s2_gemm8<<<dim3(8 * 8, g), blk, 0, stream>>>(
            B + D3, WN(3), SBN(3), B + E1, 129, 129, 64, 64, 0, 1, 8, PER, WSTR(3), 64, PER);
        conv64_gemm8<<<dim3(8 * 8, g), blk, 0, stream>>>(
            B + E1, WN(4), SBN(4), B + E2, 64, 64, 1, 8, PER, WSTR(4), 64, PER);
        // f3 x2
        conv64_gemm8<<<dim3(8 * 8, g), blk, 0, stream>>>(
            B + E2, WN(5), SBN(5), B + E3, 64, 64, 1, 8, PER, WSTR(5), 64, PER);
        conv64_gemm8<<<dim3(8 * 8, g), blk, 0, stream>>>(
            B + E3, WN(6), SBN(6), B + E1, 64, 64, 1, 8, PER, WSTR(6), 64, PER);
        // f4 up (fused): combine -> G2o; upconv(f3+f2) -> D1 (128^2, tiles 4x16); conv -> D3
        combine_up_w<<<dim3(576, g), blk, 0, stream>>>(WN(7), B + G2o, WSTR(7), PER);
        upconv64_gemm<<<dim3(4 * 16, g), blk, LDSU, stream>>>(
            B + E1, B + E2, B + G2o, SBN(7), B + D1, 64, 64, 4, PER, 64, PER);
        conv64_gemm16x8<<<dim3(8 * 16, g), blk, 0, stream>>>(
            B + D1, WN(8), SBN(8), B + D3, 128, 128, 1, 8, PER, WSTR(8), 64, PER);
        // f5 up: combine -> G2o; upconv(f4+f1) -> SA (256^2, tiles 8x32); conv -> SB
        combine_up_w<<<dim3(576, g), blk, 0, stream>>>(WN(9), B + G2o, WSTR(9), PER);
        upconv64_gemm<<<dim3(8 * 32, g), blk, LDSU, stream>>>(
            B + D3, B + D2, B + G2o, SBN(9), B + SA, 128, 128, 8, PER, 64, PER);
        conv64_gemm<1><<<dim3(16 * 16, g), blk, LDS1, stream>>>(
            B + SA, WN(10), SBN(10), B + SB, 256, 256, 256, 256, 1, 1, 16, PER, WSTR(10), 64, PER);
        // recompute f0 -> SA
        conv3_gemm<<<dim3(16 * 16, g), blk, 0, stream>>>(
            xg, WN(0), SBN(0), B + SA, 256, 256, 16, 196608, WSTR(0), 64, PER);
        // c6: conv(f5 + f0) -> out
        conv64to3_gemm<<<dim3(16 * 16, g), blk, 0, stream>>>(
            B + SB, B + SA, WN(11), SBN(11), outg, 256, 256, 16, PER, WSTR(11), 64, 196608);
        #undef WN
        #undef WSTR
        #undef SBN
        n0 += g;
    }
}